// Round 1
// baseline (530.182 us; speedup 1.0000x reference)
//
#include <hip/hip_runtime.h>
#include <hip/hip_bf16.h>
#include <math.h>

#define N_NODES 10000
#define N_EDGES 160000
#define DIN 128
#define DW 512
#define NHEAD 8
#define NC 64

// ---------------- init: zero accumulators (must run every call) ----------------
__global__ void k_init(float* __restrict__ out1, float* __restrict__ den1,
                       float* __restrict__ den2, float* __restrict__ out2) {
    int i = blockIdx.x * 256 + threadIdx.x;
    if (i < N_NODES * DW) out1[i] = 0.f;
    if (i < N_NODES * NHEAD) { den1[i] = 0.f; den2[i] = 0.f; }
    if (i < N_NODES * 2 * NHEAD) out2[i] = 0.f;
}

// ---------------- feature transform: Linear + LayerNorm + LeakyReLU ----------------
__global__ __launch_bounds__(256) void k_ft(const float* __restrict__ x,
                                            const float* __restrict__ W,
                                            const float* __restrict__ b,
                                            const float* __restrict__ g,
                                            const float* __restrict__ beta,
                                            float* __restrict__ h0) {
    __shared__ float xs[DIN];
    __shared__ float red[8];
    int n = blockIdx.x, t = threadIdx.x;
    if (t < DIN) xs[t] = x[n * DIN + t];
    __syncthreads();
    float a0 = b[t], a1 = b[t + 256];
    #pragma unroll 8
    for (int k = 0; k < DIN; k++) {
        float xv = xs[k];
        a0 += xv * W[k * DW + t];
        a1 += xv * W[k * DW + t + 256];
    }
    // block-wide mean/var over 512 values
    float s = a0 + a1, sq = a0 * a0 + a1 * a1;
    for (int o = 32; o > 0; o >>= 1) { s += __shfl_down(s, o, 64); sq += __shfl_down(sq, o, 64); }
    int wid = t >> 6;
    if ((t & 63) == 0) { red[wid] = s; red[4 + wid] = sq; }
    __syncthreads();
    if (t == 0) {
        float ts = red[0] + red[1] + red[2] + red[3];
        float tq = red[4] + red[5] + red[6] + red[7];
        float mu = ts / DW;
        float var = tq / DW - mu * mu;
        red[0] = mu; red[1] = rsqrtf(var + 1e-5f);
    }
    __syncthreads();
    float mu = red[0], rs = red[1];
    float v0 = (a0 - mu) * rs * g[t] + beta[t];
    float v1 = (a1 - mu) * rs * g[t + 256] + beta[t + 256];
    v0 = v0 >= 0.f ? v0 : 0.2f * v0;
    v1 = v1 >= 0.f ? v1 : 0.2f * v1;
    h0[n * DW + t] = v0;
    h0[n * DW + t + 256] = v1;
}

// ---------------- GEMM: h1 = h0 @ W1  (16 nodes per block) ----------------
#define NT 16
__global__ __launch_bounds__(256) void k_gemm1(const float* __restrict__ h0,
                                               const float* __restrict__ W1,
                                               float* __restrict__ h1) {
    __shared__ float hs[NT][DW];
    int t = threadIdx.x;
    int nb = blockIdx.x * NT;
    for (int i = t; i < NT * DW; i += 256)
        hs[i >> 9][i & (DW - 1)] = h0[(nb + (i >> 9)) * DW + (i & (DW - 1))];
    __syncthreads();
    float acc[NT][2];
    #pragma unroll
    for (int i = 0; i < NT; i++) { acc[i][0] = 0.f; acc[i][1] = 0.f; }
    for (int k = 0; k < DW; k++) {
        float w0 = W1[k * DW + t], w1 = W1[k * DW + t + 256];
        #pragma unroll
        for (int i = 0; i < NT; i++) {
            float hv = hs[i][k];
            acc[i][0] += hv * w0;
            acc[i][1] += hv * w1;
        }
    }
    for (int i = 0; i < NT; i++) {
        h1[(nb + i) * DW + t] = acc[i][0];
        h1[(nb + i) * DW + t + 256] = acc[i][1];
    }
}

// ---------------- attention dots layer 1: one wave per (n,h) ----------------
__global__ __launch_bounds__(256) void k_att1(const float* __restrict__ h1,
                                              const float* __restrict__ asrc,
                                              const float* __restrict__ adst,
                                              float* __restrict__ a_s,
                                              float* __restrict__ a_d) {
    int t = threadIdx.x;
    int wid = t >> 6, lane = t & 63;
    int idx = blockIdx.x * 4 + wid;      // n*NHEAD + h
    if (idx >= N_NODES * NHEAD) return;
    int n = idx >> 3, h = idx & 7;
    float hv = h1[n * DW + h * NC + lane];
    float vs = hv * asrc[h * NC + lane];
    float vd = hv * adst[h * NC + lane];
    for (int o = 32; o > 0; o >>= 1) { vs += __shfl_down(vs, o, 64); vd += __shfl_down(vd, o, 64); }
    if (lane == 0) { a_s[idx] = vs; a_d[idx] = vd; }
}

// ---------------- edge weights: w = exp(leaky(a_src[s]+a_dst[d])), denom += w ----------------
__global__ void k_edge(const int* __restrict__ ei, const float* __restrict__ a_s,
                       const float* __restrict__ a_d, float* __restrict__ w,
                       float* __restrict__ denom) {
    int idx = blockIdx.x * 256 + threadIdx.x;   // e*8 + h
    if (idx >= N_EDGES * NHEAD) return;
    int e = idx >> 3, h = idx & 7;
    int s = ei[e], d = ei[N_EDGES + e];
    float l = a_s[s * NHEAD + h] + a_d[d * NHEAD + h];
    l = l >= 0.f ? l : 0.2f * l;
    float ww = __expf(l);   // softmax shift-invariant; logits are O(1), no overflow
    w[idx] = ww;
    atomicAdd(&denom[d * NHEAD + h], ww);
}

// ---------------- aggregation layer 1: one wave per edge ----------------
__global__ __launch_bounds__(256) void k_agg1(const int* __restrict__ ei,
                                              const float* __restrict__ h1,
                                              const float* __restrict__ w,
                                              const float* __restrict__ denom,
                                              float* __restrict__ out1) {
    int t = threadIdx.x;
    int wid = t >> 6, lane = t & 63;
    int e = blockIdx.x * 4 + wid;
    if (e >= N_EDGES) return;
    int s = ei[e], d = ei[N_EDGES + e];
    const float* hrow = h1 + s * DW;
    float* orow = out1 + d * DW;
    #pragma unroll
    for (int h = 0; h < NHEAD; h++) {
        float alpha = w[e * NHEAD + h] / denom[d * NHEAD + h];
        atomicAdd(&orow[h * NC + lane], hrow[h * NC + lane] * alpha);
    }
}

// ---------------- epilogue 1: +b1, BatchNorm(eval), ReLU ----------------
__global__ void k_bn(const float* __restrict__ out1, const float* __restrict__ b1,
                     const float* __restrict__ m, const float* __restrict__ v,
                     const float* __restrict__ g, const float* __restrict__ b,
                     float* __restrict__ h2) {
    int i = blockIdx.x * 256 + threadIdx.x;
    if (i >= N_NODES * DW) return;
    int j = i & (DW - 1);
    float xv = out1[i] + b1[j];
    xv = (xv - m[j]) * rsqrtf(v[j] + 1e-5f) * g[j] + b[j];
    h2[i] = xv > 0.f ? xv : 0.f;
}

// ---------------- GEMM2: g = h2 @ W2 [512,16] ----------------
__global__ __launch_bounds__(256) void k_gemm2(const float* __restrict__ h2,
                                               const float* __restrict__ W2,
                                               float* __restrict__ gout) {
    __shared__ float Ws[DW * 16];
    int t = threadIdx.x;
    for (int i = t; i < DW * 16; i += 256) Ws[i] = W2[i];
    __syncthreads();
    int nb = blockIdx.x * 16;
    int nl = t >> 4, j = t & 15;
    const float* hr = h2 + (nb + nl) * DW;
    float acc = 0.f;
    for (int k = 0; k < DW; k++) acc += hr[k] * Ws[k * 16 + j];
    gout[(nb + nl) * 16 + j] = acc;
}

// ---------------- attention dots layer 2 ----------------
__global__ void k_att2(const float* __restrict__ gout, const float* __restrict__ as2,
                       const float* __restrict__ ad2, float* __restrict__ a_s,
                       float* __restrict__ a_d) {
    int idx = blockIdx.x * 256 + threadIdx.x;   // n*8 + h
    if (idx >= N_NODES * NHEAD) return;
    int n = idx >> 3, h = idx & 7;
    float g0 = gout[n * 16 + 2 * h], g1 = gout[n * 16 + 2 * h + 1];
    a_s[idx] = g0 * as2[2 * h] + g1 * as2[2 * h + 1];
    a_d[idx] = g0 * ad2[2 * h] + g1 * ad2[2 * h + 1];
}

// ---------------- aggregation layer 2: thread per (edge, j) ----------------
__global__ void k_agg2(const int* __restrict__ ei, const float* __restrict__ gout,
                       const float* __restrict__ w, const float* __restrict__ denom,
                       float* __restrict__ out2) {
    int idx = blockIdx.x * 256 + threadIdx.x;   // e*16 + j
    if (idx >= N_EDGES * 16) return;
    int e = idx >> 4, j = idx & 15, h = j >> 1;
    int s = ei[e], d = ei[N_EDGES + e];
    float alpha = w[e * NHEAD + h] / denom[d * NHEAD + h];
    atomicAdd(&out2[d * 16 + j], gout[s * 16 + j] * alpha);
}

// ---------------- final: mean over heads + b2 ----------------
__global__ void k_final(const float* __restrict__ out2, const float* __restrict__ b2,
                        float* __restrict__ out) {
    int i = blockIdx.x * 256 + threadIdx.x;   // n*2 + c
    if (i >= N_NODES * 2) return;
    int n = i >> 1, c = i & 1;
    float s = 0.f;
    #pragma unroll
    for (int h = 0; h < NHEAD; h++) s += out2[n * 16 + h * 2 + c];
    out[i] = s * (1.f / NHEAD) + b2[c];
}

extern "C" void kernel_launch(void* const* d_in, const int* in_sizes, int n_in,
                              void* d_out, int out_size, void* d_ws, size_t ws_size,
                              hipStream_t stream) {
    const float* x    = (const float*)d_in[0];
    const int*   ei   = (const int*)d_in[1];
    const float* ftW  = (const float*)d_in[2];
    const float* ftb  = (const float*)d_in[3];
    const float* lng  = (const float*)d_in[4];
    const float* lnb  = (const float*)d_in[5];
    const float* W1   = (const float*)d_in[6];
    const float* as1  = (const float*)d_in[7];
    const float* ad1  = (const float*)d_in[8];
    const float* b1   = (const float*)d_in[9];
    const float* bng  = (const float*)d_in[10];
    const float* bnb  = (const float*)d_in[11];
    const float* bnm  = (const float*)d_in[12];
    const float* bnv  = (const float*)d_in[13];
    const float* W2   = (const float*)d_in[14];
    const float* as2  = (const float*)d_in[15];
    const float* ad2  = (const float*)d_in[16];
    const float* b2   = (const float*)d_in[17];
    float* out = (float*)d_out;

    float* F = (float*)d_ws;
    float* h0   = F;                    // 5,120,000   (reused as h2)
    float* h1   = F + 5120000;          // 5,120,000
    float* out1 = F + 10240000;         // 5,120,000
    float* aS1  = F + 15360000;         // 80,000
    float* aD1  = F + 15440000;         // 80,000
    float* den1 = F + 15520000;         // 80,000
    float* wE1  = F + 15600000;         // 1,280,000
    float* gbuf = F + 16880000;         // 160,000
    float* aS2  = F + 17040000;         // 80,000
    float* aD2  = F + 17120000;         // 80,000
    float* den2 = F + 17200000;         // 80,000
    float* wE2  = F + 17280000;         // 1,280,000
    float* out2 = F + 18560000;         // 160,000  -> total 18,720,000 f = 74.9 MB

    k_init<<<(N_NODES * DW + 255) / 256, 256, 0, stream>>>(out1, den1, den2, out2);
    k_ft<<<N_NODES, 256, 0, stream>>>(x, ftW, ftb, lng, lnb, h0);
    k_gemm1<<<N_NODES / NT, 256, 0, stream>>>(h0, W1, h1);
    k_att1<<<(N_NODES * NHEAD) / 4, 256, 0, stream>>>(h1, as1, ad1, aS1, aD1);
    k_edge<<<(N_EDGES * NHEAD + 255) / 256, 256, 0, stream>>>(ei, aS1, aD1, wE1, den1);
    k_agg1<<<N_EDGES / 4, 256, 0, stream>>>(ei, h1, wE1, den1, out1);
    k_bn<<<(N_NODES * DW + 255) / 256, 256, 0, stream>>>(out1, b1, bnm, bnv, bng, bnb, h0);
    k_gemm2<<<N_NODES / 16, 256, 0, stream>>>(h0, W2, gbuf);
    k_att2<<<(N_NODES * NHEAD + 255) / 256, 256, 0, stream>>>(gbuf, as2, ad2, aS2, aD2);
    k_edge<<<(N_EDGES * NHEAD + 255) / 256, 256, 0, stream>>>(ei, aS2, aD2, wE2, den2);
    k_agg2<<<(N_EDGES * 16 + 255) / 256, 256, 0, stream>>>(ei, gbuf, wE2, den2, out2);
    k_final<<<(N_NODES * 2 + 255) / 256, 256, 0, stream>>>(out2, b2, out);
}

// Round 2
// 310.527 us; speedup vs baseline: 1.7074x; 1.7074x over previous
//
#include <hip/hip_runtime.h>
#include <hip/hip_bf16.h>
#include <math.h>

#define N_NODES 10000
#define N_EDGES 160000
#define DIN 128
#define DW 512
#define NHEAD 8
#define NC 64

// ================= CSR build =================
__global__ void k_zero(int* __restrict__ cnt, int* __restrict__ cursor) {
    int i = blockIdx.x * 256 + threadIdx.x;
    if (i < N_NODES) { cnt[i] = 0; cursor[i] = 0; }
}

__global__ void k_count(const int* __restrict__ ei, int* __restrict__ cnt) {
    int e = blockIdx.x * 256 + threadIdx.x;
    if (e < N_EDGES) atomicAdd(&cnt[ei[N_EDGES + e]], 1);
}

// exclusive prefix sum over 10000 counts -> off[0..N_NODES]
__global__ __launch_bounds__(256) void k_scan(const int* __restrict__ cnt, int* __restrict__ off) {
    __shared__ int ps[256];
    int t = threadIdx.x;
    int base = t * 40;                      // 256*40 = 10240 >= 10000
    int loc[40];
    int s = 0;
    #pragma unroll
    for (int i = 0; i < 40; i++) {
        int idx = base + i;
        int v = idx < N_NODES ? cnt[idx] : 0;
        loc[i] = s; s += v;
    }
    ps[t] = s; __syncthreads();
    for (int o = 1; o < 256; o <<= 1) {
        int v = (t >= o) ? ps[t - o] : 0;
        __syncthreads();
        ps[t] += v;
        __syncthreads();
    }
    int pre = (t > 0) ? ps[t - 1] : 0;
    #pragma unroll
    for (int i = 0; i < 40; i++) {
        int idx = base + i;
        if (idx < N_NODES) off[idx] = pre + loc[i];
    }
    if (t == 255) off[N_NODES] = ps[255];
}

__global__ void k_scatter(const int* __restrict__ ei, const int* __restrict__ off,
                          int* __restrict__ cursor, int* __restrict__ csrc) {
    int e = blockIdx.x * 256 + threadIdx.x;
    if (e < N_EDGES) {
        int d = ei[N_EDGES + e];
        int p = off[d] + atomicAdd(&cursor[d], 1);
        csrc[p] = ei[e];
    }
}

// ================= feature transform: Linear + LayerNorm + LeakyReLU =================
__global__ __launch_bounds__(256) void k_ft(const float* __restrict__ x,
                                            const float* __restrict__ W,
                                            const float* __restrict__ b,
                                            const float* __restrict__ g,
                                            const float* __restrict__ beta,
                                            float* __restrict__ h0) {
    __shared__ float xs[DIN];
    __shared__ float red[8];
    int n = blockIdx.x, t = threadIdx.x;
    if (t < DIN) xs[t] = x[n * DIN + t];
    __syncthreads();
    float a0 = b[t], a1 = b[t + 256];
    #pragma unroll 8
    for (int k = 0; k < DIN; k++) {
        float xv = xs[k];
        a0 += xv * W[k * DW + t];
        a1 += xv * W[k * DW + t + 256];
    }
    float s = a0 + a1, sq = a0 * a0 + a1 * a1;
    for (int o = 32; o > 0; o >>= 1) { s += __shfl_down(s, o, 64); sq += __shfl_down(sq, o, 64); }
    int wid = t >> 6;
    if ((t & 63) == 0) { red[wid] = s; red[4 + wid] = sq; }
    __syncthreads();
    if (t == 0) {
        float ts = red[0] + red[1] + red[2] + red[3];
        float tq = red[4] + red[5] + red[6] + red[7];
        float mu = ts / DW;
        float var = tq / DW - mu * mu;
        red[0] = mu; red[1] = rsqrtf(var + 1e-5f);
    }
    __syncthreads();
    float mu = red[0], rs = red[1];
    float v0 = (a0 - mu) * rs * g[t] + beta[t];
    float v1 = (a1 - mu) * rs * g[t + 256] + beta[t + 256];
    v0 = v0 >= 0.f ? v0 : 0.2f * v0;
    v1 = v1 >= 0.f ? v1 : 0.2f * v1;
    h0[n * DW + t] = v0;
    h0[n * DW + t + 256] = v1;
}

// ================= GEMM1: h1 = h0 @ W1 (16 nodes / block) =================
#define NT 16
__global__ __launch_bounds__(256) void k_gemm1(const float* __restrict__ h0,
                                               const float* __restrict__ W1,
                                               float* __restrict__ h1) {
    __shared__ float hs[NT][DW];
    int t = threadIdx.x;
    int nb = blockIdx.x * NT;
    for (int i = t; i < NT * DW; i += 256)
        hs[i >> 9][i & (DW - 1)] = h0[(nb + (i >> 9)) * DW + (i & (DW - 1))];
    __syncthreads();
    float acc[NT][2];
    #pragma unroll
    for (int i = 0; i < NT; i++) { acc[i][0] = 0.f; acc[i][1] = 0.f; }
    for (int k = 0; k < DW; k++) {
        float w0 = W1[k * DW + t], w1 = W1[k * DW + t + 256];
        #pragma unroll
        for (int i = 0; i < NT; i++) {
            float hv = hs[i][k];
            acc[i][0] += hv * w0;
            acc[i][1] += hv * w1;
        }
    }
    for (int i = 0; i < NT; i++) {
        h1[(nb + i) * DW + t] = acc[i][0];
        h1[(nb + i) * DW + t + 256] = acc[i][1];
    }
}

// ================= attention dots layer 1 =================
__global__ __launch_bounds__(256) void k_att1(const float* __restrict__ h1,
                                              const float* __restrict__ asrc,
                                              const float* __restrict__ adst,
                                              float* __restrict__ a_s,
                                              float* __restrict__ a_d) {
    int t = threadIdx.x;
    int wid = t >> 6, lane = t & 63;
    int idx = blockIdx.x * 4 + wid;      // n*NHEAD + h
    if (idx >= N_NODES * NHEAD) return;
    int n = idx >> 3, h = idx & 7;
    float hv = h1[n * DW + h * NC + lane];
    float vs = hv * asrc[h * NC + lane];
    float vd = hv * adst[h * NC + lane];
    for (int o = 32; o > 0; o >>= 1) { vs += __shfl_down(vs, o, 64); vd += __shfl_down(vd, o, 64); }
    if (lane == 0) { a_s[idx] = vs; a_d[idx] = vd; }
}

// ================= layer-1 aggregation, CSR, fused softmax + bias + BN + ReLU =================
// out = (sum_e w_e * h1[src_e]) / (sum_e w_e)  -- denominator divides out, single pass.
__global__ __launch_bounds__(256) void k_agg1csr(
    const int* __restrict__ csrc, const int* __restrict__ off,
    const float* __restrict__ h1,
    const float* __restrict__ aS, const float* __restrict__ aD,
    const float* __restrict__ b1, const float* __restrict__ bnm,
    const float* __restrict__ bnv, const float* __restrict__ bng,
    const float* __restrict__ bnb, float* __restrict__ h2)
{
    int n = blockIdx.x, t = threadIdx.x;
    int beg = off[n], end = off[n + 1];
    __shared__ float wls[64][NHEAD];
    __shared__ int   sls[64];
    __shared__ float aDn[NHEAD];
    __shared__ float dsum[NHEAD];
    if (t < NHEAD) { aDn[t] = aD[n * NHEAD + t]; dsum[t] = 0.f; }
    __syncthreads();
    float acc0 = 0.f, acc1 = 0.f, dpart = 0.f;
    int hA = t >> 6, hB = 4 + (t >> 6);     // heads owning cols t and t+256
    for (int c = beg; c < end; c += 64) {
        int m = min(64, end - c);
        if (t < m) sls[t] = csrc[c + t];
        __syncthreads();
        for (int idx = t; idx < m * NHEAD; idx += 256) {
            int el = idx >> 3, h = idx & 7;          // h == t&7 always (256 % 8 == 0)
            float l = aS[sls[el] * NHEAD + h] + aDn[h];
            l = l >= 0.f ? l : 0.2f * l;
            float w = __expf(l);                     // shift-invariant; logits O(1)
            wls[el][h] = w;
            dpart += w;
        }
        __syncthreads();
        for (int el = 0; el < m; el++) {
            const float* hr = h1 + sls[el] * DW;
            acc0 += wls[el][hA] * hr[t];
            acc1 += wls[el][hB] * hr[t + 256];
        }
        __syncthreads();
    }
    // reduce dpart (thread t holds partial for head t&7): lanes l, l+8, .. l+56
    for (int o = 8; o < 64; o <<= 1) dpart += __shfl_down(dpart, o, 64);
    if ((t & 63) < NHEAD) atomicAdd(&dsum[t & 7], dpart);
    __syncthreads();
    float rdA = dsum[hA] > 0.f ? 1.f / dsum[hA] : 0.f;
    float rdB = dsum[hB] > 0.f ? 1.f / dsum[hB] : 0.f;
    int j0 = t, j1 = t + 256;
    float v0 = acc0 * rdA + b1[j0];
    v0 = (v0 - bnm[j0]) * rsqrtf(bnv[j0] + 1e-5f) * bng[j0] + bnb[j0];
    v0 = v0 > 0.f ? v0 : 0.f;
    float v1 = acc1 * rdB + b1[j1];
    v1 = (v1 - bnm[j1]) * rsqrtf(bnv[j1] + 1e-5f) * bng[j1] + bnb[j1];
    v1 = v1 > 0.f ? v1 : 0.f;
    h2[n * DW + j0] = v0;
    h2[n * DW + j1] = v1;
}

// ================= GEMM2: g = h2 @ W2 [512,16] =================
__global__ __launch_bounds__(256) void k_gemm2(const float* __restrict__ h2,
                                               const float* __restrict__ W2,
                                               float* __restrict__ gout) {
    __shared__ float Ws[DW * 16];
    int t = threadIdx.x;
    for (int i = t; i < DW * 16; i += 256) Ws[i] = W2[i];
    __syncthreads();
    int nb = blockIdx.x * 16;
    int nl = t >> 4, j = t & 15;
    const float* hr = h2 + (nb + nl) * DW;
    float acc = 0.f;
    for (int k = 0; k < DW; k++) acc += hr[k] * Ws[k * 16 + j];
    gout[(nb + nl) * 16 + j] = acc;
}

// ================= attention dots layer 2 =================
__global__ void k_att2(const float* __restrict__ gout, const float* __restrict__ as2,
                       const float* __restrict__ ad2, float* __restrict__ a_s,
                       float* __restrict__ a_d) {
    int idx = blockIdx.x * 256 + threadIdx.x;   // n*8 + h
    if (idx >= N_NODES * NHEAD) return;
    int n = idx >> 3, h = idx & 7;
    float g0 = gout[n * 16 + 2 * h], g1 = gout[n * 16 + 2 * h + 1];
    a_s[idx] = g0 * as2[2 * h] + g1 * as2[2 * h + 1];
    a_d[idx] = g0 * ad2[2 * h] + g1 * ad2[2 * h + 1];
}

// ================= layer-2 aggregation, CSR, fused head-mean + b2 -> final out =================
// one wave per node; lanes: j = lane&15 (col), slot = lane>>4 (edge parallelism 4)
__global__ __launch_bounds__(256) void k_agg2csr(
    const int* __restrict__ csrc, const int* __restrict__ off,
    const float* __restrict__ gbuf,
    const float* __restrict__ aS, const float* __restrict__ aD,
    const float* __restrict__ b2, float* __restrict__ outp)
{
    int t = threadIdx.x;
    int n = blockIdx.x * 4 + (t >> 6);
    int lane = t & 63;
    if (n >= N_NODES) return;
    int beg = off[n], end = off[n + 1];
    int j = lane & 15, slot = lane >> 4, h = j >> 1;
    float adn = aD[n * NHEAD + h];
    float acc = 0.f, den = 0.f;
    for (int c = beg + slot; c < end; c += 4) {
        int s = csrc[c];
        float l = aS[s * NHEAD + h] + adn;
        l = l >= 0.f ? l : 0.2f * l;
        float w = __expf(l);
        den += w;
        acc += w * gbuf[s * 16 + j];
    }
    acc += __shfl_down(acc, 16, 64); acc += __shfl_down(acc, 32, 64);
    den += __shfl_down(den, 16, 64); den += __shfl_down(den, 32, 64);
    float v = (lane < 16 && den > 0.f) ? acc / den : 0.f;
    // head mean: sum cols j, j+2, ..  (lanes >=16 contribute zeros)
    v += __shfl_down(v, 2, 64);
    v += __shfl_down(v, 4, 64);
    v += __shfl_down(v, 8, 64);
    if (lane < 2) outp[n * 2 + lane] = v * 0.125f + b2[lane];
}

extern "C" void kernel_launch(void* const* d_in, const int* in_sizes, int n_in,
                              void* d_out, int out_size, void* d_ws, size_t ws_size,
                              hipStream_t stream) {
    const float* x    = (const float*)d_in[0];
    const int*   ei   = (const int*)d_in[1];
    const float* ftW  = (const float*)d_in[2];
    const float* ftb  = (const float*)d_in[3];
    const float* lng  = (const float*)d_in[4];
    const float* lnb  = (const float*)d_in[5];
    const float* W1   = (const float*)d_in[6];
    const float* as1  = (const float*)d_in[7];
    const float* ad1  = (const float*)d_in[8];
    const float* b1   = (const float*)d_in[9];
    const float* bng  = (const float*)d_in[10];
    const float* bnb  = (const float*)d_in[11];
    const float* bnm  = (const float*)d_in[12];
    const float* bnv  = (const float*)d_in[13];
    const float* W2   = (const float*)d_in[14];
    const float* as2  = (const float*)d_in[15];
    const float* ad2  = (const float*)d_in[16];
    const float* b2   = (const float*)d_in[17];
    float* out = (float*)d_out;

    float* F = (float*)d_ws;
    float* h0   = F;                    // 5,120,000
    float* h1   = F + 5120000;          // 5,120,000
    float* h2   = F + 10240000;         // 5,120,000
    float* aS1  = F + 15360000;         // 80,000
    float* aD1  = F + 15440000;         // 80,000
    float* gbuf = F + 15520000;         // 160,000
    float* aS2  = F + 15680000;         // 80,000
    float* aD2  = F + 15760000;         // 80,000
    int* I = (int*)(F + 15840000);
    int* cnt    = I;                    // 10,000
    int* off    = I + 10000;            // 10,001
    int* cursor = I + 20001;            // 10,000
    int* csrc   = I + 30001;            // 160,000  (total ~64.1 MB)

    // CSR build (independent of features)
    k_zero<<<40, 256, 0, stream>>>(cnt, cursor);
    k_count<<<(N_EDGES + 255) / 256, 256, 0, stream>>>(ei, cnt);
    k_scan<<<1, 256, 0, stream>>>(cnt, off);
    k_scatter<<<(N_EDGES + 255) / 256, 256, 0, stream>>>(ei, off, cursor, csrc);

    k_ft<<<N_NODES, 256, 0, stream>>>(x, ftW, ftb, lng, lnb, h0);
    k_gemm1<<<N_NODES / NT, 256, 0, stream>>>(h0, W1, h1);
    k_att1<<<(N_NODES * NHEAD) / 4, 256, 0, stream>>>(h1, as1, ad1, aS1, aD1);
    k_agg1csr<<<N_NODES, 256, 0, stream>>>(csrc, off, h1, aS1, aD1, b1, bnm, bnv, bng, bnb, h2);
    k_gemm2<<<N_NODES / 16, 256, 0, stream>>>(h2, W2, gbuf);
    k_att2<<<(N_NODES * NHEAD + 255) / 256, 256, 0, stream>>>(gbuf, as2, ad2, aS2, aD2);
    k_agg2csr<<<(N_NODES + 3) / 4, 256, 0, stream>>>(csrc, off, gbuf, aS2, aD2, b2, out);
}

// Round 3
// 256.866 us; speedup vs baseline: 2.0640x; 1.2089x over previous
//
#include <hip/hip_runtime.h>
#include <hip/hip_bf16.h>
#include <math.h>

#define N_NODES 10000
#define N_EDGES 160000
#define DIN 128
#define DW 512
#define NHEAD 8
#define NC 64

typedef __attribute__((ext_vector_type(8))) short bf16x8;
typedef __attribute__((ext_vector_type(4))) float f32x4;

// ================= CSR build =================
__global__ void k_zero(int* __restrict__ cnt, int* __restrict__ cursor) {
    int i = blockIdx.x * 256 + threadIdx.x;
    if (i < N_NODES) { cnt[i] = 0; cursor[i] = 0; }
}

__global__ void k_count(const int* __restrict__ ei, int* __restrict__ cnt) {
    int e = blockIdx.x * 256 + threadIdx.x;
    if (e < N_EDGES) atomicAdd(&cnt[ei[N_EDGES + e]], 1);
}

__global__ __launch_bounds__(256) void k_scan(const int* __restrict__ cnt, int* __restrict__ off) {
    __shared__ int ps[256];
    int t = threadIdx.x;
    int base = t * 40;
    int loc[40];
    int s = 0;
    #pragma unroll
    for (int i = 0; i < 40; i++) {
        int idx = base + i;
        int v = idx < N_NODES ? cnt[idx] : 0;
        loc[i] = s; s += v;
    }
    ps[t] = s; __syncthreads();
    for (int o = 1; o < 256; o <<= 1) {
        int v = (t >= o) ? ps[t - o] : 0;
        __syncthreads();
        ps[t] += v;
        __syncthreads();
    }
    int pre = (t > 0) ? ps[t - 1] : 0;
    #pragma unroll
    for (int i = 0; i < 40; i++) {
        int idx = base + i;
        if (idx < N_NODES) off[idx] = pre + loc[i];
    }
    if (t == 255) off[N_NODES] = ps[255];
}

__global__ void k_scatter(const int* __restrict__ ei, const int* __restrict__ off,
                          int* __restrict__ cursor, int* __restrict__ csrc) {
    int e = blockIdx.x * 256 + threadIdx.x;
    if (e < N_EDGES) {
        int d = ei[N_EDGES + e];
        int p = off[d] + atomicAdd(&cursor[d], 1);
        csrc[p] = ei[e];
    }
}

// ================= f32 -> bf16 hi/lo split converters =================
__global__ void k_cvtx(const float* __restrict__ x, __hip_bfloat16* __restrict__ hi,
                       __hip_bfloat16* __restrict__ lo, int n) {
    int i = blockIdx.x * 256 + threadIdx.x;
    if (i >= n) return;
    float v = x[i];
    __hip_bfloat16 h = __float2bfloat16(v);
    hi[i] = h;
    lo[i] = __float2bfloat16(v - __bfloat162float(h));
}

// W [K][512] f32 -> WT hi/lo [512][K] bf16 (transpose + split)
__global__ void k_cvtT(const float* __restrict__ W, __hip_bfloat16* __restrict__ hi,
                       __hip_bfloat16* __restrict__ lo, int K) {
    int i = blockIdx.x * 256 + threadIdx.x;
    if (i >= K * 512) return;
    int k = i >> 9, n = i & 511;
    float v = W[i];
    __hip_bfloat16 h = __float2bfloat16(v);
    hi[n * K + k] = h;
    lo[n * K + k] = __float2bfloat16(v - __bfloat162float(h));
}

// ================= split-bf16 MFMA GEMM: C[M][512] = A[M][KD] @ BT[512][KD]^T =================
// block: 128 rows x 256 cols, 4 waves; wave = 2 rowfrags x 16 colfrags (16x16x32 MFMA)
// 3-term split precision: C = Ahi*Bhi + Alo*Bhi + Ahi*Blo  (~f32 accuracy)
template<int KD>
__global__ __launch_bounds__(256) void k_mgemm(
    const __hip_bfloat16* __restrict__ Ahi, const __hip_bfloat16* __restrict__ Alo,
    const __hip_bfloat16* __restrict__ BThi, const __hip_bfloat16* __restrict__ BTlo,
    float* __restrict__ C, int M)
{
    int t = threadIdx.x, w = t >> 6, l = t & 63;
    int lm = l & 15, g = l >> 4;
    int rowbase = blockIdx.x * 128 + w * 32;
    int colbase = blockIdx.y * 256;
    int ra = min(rowbase + lm, M - 1);
    int rb = min(rowbase + 16 + lm, M - 1);
    const bf16x8* pA0h = (const bf16x8*)(Ahi + (size_t)ra * KD) + g;
    const bf16x8* pA0l = (const bf16x8*)(Alo + (size_t)ra * KD) + g;
    const bf16x8* pA1h = (const bf16x8*)(Ahi + (size_t)rb * KD) + g;
    const bf16x8* pA1l = (const bf16x8*)(Alo + (size_t)rb * KD) + g;
    const bf16x8* pBh  = (const bf16x8*)(BThi + (size_t)(colbase + lm) * KD) + g;
    const bf16x8* pBl  = (const bf16x8*)(BTlo + (size_t)(colbase + lm) * KD) + g;
    const int CST = 2 * KD;              // bf16x8 units per 16-col step

    f32x4 acc[2][16];
    #pragma unroll
    for (int r = 0; r < 2; r++)
        #pragma unroll
        for (int c = 0; c < 16; c++) acc[r][c] = (f32x4){0.f, 0.f, 0.f, 0.f};

    #pragma unroll 2
    for (int ks = 0; ks < KD / 32; ks++) {
        bf16x8 a0h = pA0h[ks * 4], a0l = pA0l[ks * 4];
        bf16x8 a1h = pA1h[ks * 4], a1l = pA1l[ks * 4];
        #pragma unroll
        for (int c = 0; c < 16; c++) {
            bf16x8 bh = pBh[c * CST + ks * 4];
            bf16x8 bl = pBl[c * CST + ks * 4];
            acc[0][c] = __builtin_amdgcn_mfma_f32_16x16x32_bf16(a0h, bh, acc[0][c], 0, 0, 0);
            acc[0][c] = __builtin_amdgcn_mfma_f32_16x16x32_bf16(a0l, bh, acc[0][c], 0, 0, 0);
            acc[0][c] = __builtin_amdgcn_mfma_f32_16x16x32_bf16(a0h, bl, acc[0][c], 0, 0, 0);
            acc[1][c] = __builtin_amdgcn_mfma_f32_16x16x32_bf16(a1h, bh, acc[1][c], 0, 0, 0);
            acc[1][c] = __builtin_amdgcn_mfma_f32_16x16x32_bf16(a1l, bh, acc[1][c], 0, 0, 0);
            acc[1][c] = __builtin_amdgcn_mfma_f32_16x16x32_bf16(a1h, bl, acc[1][c], 0, 0, 0);
        }
    }
    // C/D layout (HW-verified): col = lane&15, row = (lane>>4)*4 + reg
    #pragma unroll
    for (int r = 0; r < 2; r++)
        #pragma unroll
        for (int c = 0; c < 16; c++) {
            int row = rowbase + r * 16 + g * 4;
            int col = colbase + c * 16 + lm;
            #pragma unroll
            for (int q = 0; q < 4; q++)
                if (row + q < M) C[(size_t)(row + q) * DW + col] = acc[r][c][q];
        }
}

// ================= LN epilogue: hpre + ftb -> LayerNorm -> LeakyReLU -> bf16 hi/lo =================
__global__ __launch_bounds__(256) void k_ln(const float* __restrict__ hpre,
                                            const float* __restrict__ fb,
                                            const float* __restrict__ g,
                                            const float* __restrict__ beta,
                                            __hip_bfloat16* __restrict__ hi,
                                            __hip_bfloat16* __restrict__ lo) {
    __shared__ float red[8];
    int n = blockIdx.x, t = threadIdx.x;
    float a0 = hpre[n * DW + t] + fb[t];
    float a1 = hpre[n * DW + t + 256] + fb[t + 256];
    float s = a0 + a1, sq = a0 * a0 + a1 * a1;
    for (int o = 32; o > 0; o >>= 1) { s += __shfl_down(s, o, 64); sq += __shfl_down(sq, o, 64); }
    int wid = t >> 6;
    if ((t & 63) == 0) { red[wid] = s; red[4 + wid] = sq; }
    __syncthreads();
    if (t == 0) {
        float ts = red[0] + red[1] + red[2] + red[3];
        float tq = red[4] + red[5] + red[6] + red[7];
        float mu = ts / DW;
        float var = tq / DW - mu * mu;
        red[0] = mu; red[1] = rsqrtf(var + 1e-5f);
    }
    __syncthreads();
    float mu = red[0], rs = red[1];
    float v0 = (a0 - mu) * rs * g[t] + beta[t];
    float v1 = (a1 - mu) * rs * g[t + 256] + beta[t + 256];
    v0 = v0 >= 0.f ? v0 : 0.2f * v0;
    v1 = v1 >= 0.f ? v1 : 0.2f * v1;
    __hip_bfloat16 h0 = __float2bfloat16(v0);
    __hip_bfloat16 h1 = __float2bfloat16(v1);
    hi[n * DW + t] = h0;
    lo[n * DW + t] = __float2bfloat16(v0 - __bfloat162float(h0));
    hi[n * DW + t + 256] = h1;
    lo[n * DW + t + 256] = __float2bfloat16(v1 - __bfloat162float(h1));
}

// ================= attention dots layer 1 =================
__global__ __launch_bounds__(256) void k_att1(const float* __restrict__ h1,
                                              const float* __restrict__ asrc,
                                              const float* __restrict__ adst,
                                              float* __restrict__ a_s,
                                              float* __restrict__ a_d) {
    int t = threadIdx.x;
    int wid = t >> 6, lane = t & 63;
    int idx = blockIdx.x * 4 + wid;      // n*NHEAD + h
    if (idx >= N_NODES * NHEAD) return;
    int n = idx >> 3, h = idx & 7;
    float hv = h1[n * DW + h * NC + lane];
    float vs = hv * asrc[h * NC + lane];
    float vd = hv * adst[h * NC + lane];
    for (int o = 32; o > 0; o >>= 1) { vs += __shfl_down(vs, o, 64); vd += __shfl_down(vd, o, 64); }
    if (lane == 0) { a_s[idx] = vs; a_d[idx] = vd; }
}

// ================= layer-1 aggregation, CSR, fused softmax + bias + BN + ReLU =================
__global__ __launch_bounds__(256) void k_agg1csr(
    const int* __restrict__ csrc, const int* __restrict__ off,
    const float* __restrict__ h1,
    const float* __restrict__ aS, const float* __restrict__ aD,
    const float* __restrict__ b1, const float* __restrict__ bnm,
    const float* __restrict__ bnv, const float* __restrict__ bng,
    const float* __restrict__ bnb, float* __restrict__ h2)
{
    int n = blockIdx.x, t = threadIdx.x;
    int beg = off[n], end = off[n + 1];
    __shared__ float wls[64][NHEAD];
    __shared__ int   sls[64];
    __shared__ float aDn[NHEAD];
    __shared__ float dsum[NHEAD];
    if (t < NHEAD) { aDn[t] = aD[n * NHEAD + t]; dsum[t] = 0.f; }
    __syncthreads();
    float acc0 = 0.f, acc1 = 0.f, dpart = 0.f;
    int hA = t >> 6, hB = 4 + (t >> 6);
    for (int c = beg; c < end; c += 64) {
        int m = min(64, end - c);
        if (t < m) sls[t] = csrc[c + t];
        __syncthreads();
        for (int idx = t; idx < m * NHEAD; idx += 256) {
            int el = idx >> 3, h = idx & 7;
            float l = aS[sls[el] * NHEAD + h] + aDn[h];
            l = l >= 0.f ? l : 0.2f * l;
            float w = __expf(l);
            wls[el][h] = w;
            dpart += w;
        }
        __syncthreads();
        for (int el = 0; el < m; el++) {
            const float* hr = h1 + (size_t)sls[el] * DW;
            acc0 += wls[el][hA] * hr[t];
            acc1 += wls[el][hB] * hr[t + 256];
        }
        __syncthreads();
    }
    for (int o = 8; o < 64; o <<= 1) dpart += __shfl_down(dpart, o, 64);
    if ((t & 63) < NHEAD) atomicAdd(&dsum[t & 7], dpart);
    __syncthreads();
    float rdA = dsum[hA] > 0.f ? 1.f / dsum[hA] : 0.f;
    float rdB = dsum[hB] > 0.f ? 1.f / dsum[hB] : 0.f;
    int j0 = t, j1 = t + 256;
    float v0 = acc0 * rdA + b1[j0];
    v0 = (v0 - bnm[j0]) * rsqrtf(bnv[j0] + 1e-5f) * bng[j0] + bnb[j0];
    v0 = v0 > 0.f ? v0 : 0.f;
    float v1 = acc1 * rdB + b1[j1];
    v1 = (v1 - bnm[j1]) * rsqrtf(bnv[j1] + 1e-5f) * bng[j1] + bnb[j1];
    v1 = v1 > 0.f ? v1 : 0.f;
    h2[n * DW + j0] = v0;
    h2[n * DW + j1] = v1;
}

// ================= GEMM2: g = h2 @ W2 [512,16] =================
__global__ __launch_bounds__(256) void k_gemm2(const float* __restrict__ h2,
                                               const float* __restrict__ W2,
                                               float* __restrict__ gout) {
    __shared__ float Ws[DW * 16];
    int t = threadIdx.x;
    for (int i = t; i < DW * 16; i += 256) Ws[i] = W2[i];
    __syncthreads();
    int nb = blockIdx.x * 16;
    int nl = t >> 4, j = t & 15;
    const float* hr = h2 + (size_t)(nb + nl) * DW;
    float acc = 0.f;
    for (int k = 0; k < DW; k++) acc += hr[k] * Ws[k * 16 + j];
    gout[(nb + nl) * 16 + j] = acc;
}

// ================= attention dots layer 2 =================
__global__ void k_att2(const float* __restrict__ gout, const float* __restrict__ as2,
                       const float* __restrict__ ad2, float* __restrict__ a_s,
                       float* __restrict__ a_d) {
    int idx = blockIdx.x * 256 + threadIdx.x;
    if (idx >= N_NODES * NHEAD) return;
    int n = idx >> 3, h = idx & 7;
    float g0 = gout[n * 16 + 2 * h], g1 = gout[n * 16 + 2 * h + 1];
    a_s[idx] = g0 * as2[2 * h] + g1 * as2[2 * h + 1];
    a_d[idx] = g0 * ad2[2 * h] + g1 * ad2[2 * h + 1];
}

// ================= layer-2 aggregation, CSR, fused head-mean + b2 =================
__global__ __launch_bounds__(256) void k_agg2csr(
    const int* __restrict__ csrc, const int* __restrict__ off,
    const float* __restrict__ gbuf,
    const float* __restrict__ aS, const float* __restrict__ aD,
    const float* __restrict__ b2, float* __restrict__ outp)
{
    int t = threadIdx.x;
    int n = blockIdx.x * 4 + (t >> 6);
    int lane = t & 63;
    if (n >= N_NODES) return;
    int beg = off[n], end = off[n + 1];
    int j = lane & 15, slot = lane >> 4, h = j >> 1;
    float adn = aD[n * NHEAD + h];
    float acc = 0.f, den = 0.f;
    for (int c = beg + slot; c < end; c += 4) {
        int s = csrc[c];
        float l = aS[s * NHEAD + h] + adn;
        l = l >= 0.f ? l : 0.2f * l;
        float w = __expf(l);
        den += w;
        acc += w * gbuf[s * 16 + j];
    }
    acc += __shfl_down(acc, 16, 64); acc += __shfl_down(acc, 32, 64);
    den += __shfl_down(den, 16, 64); den += __shfl_down(den, 32, 64);
    float v = (lane < 16 && den > 0.f) ? acc / den : 0.f;
    v += __shfl_down(v, 2, 64);
    v += __shfl_down(v, 4, 64);
    v += __shfl_down(v, 8, 64);
    if (lane < 2) outp[n * 2 + lane] = v * 0.125f + b2[lane];
}

extern "C" void kernel_launch(void* const* d_in, const int* in_sizes, int n_in,
                              void* d_out, int out_size, void* d_ws, size_t ws_size,
                              hipStream_t stream) {
    const float* x    = (const float*)d_in[0];
    const int*   ei   = (const int*)d_in[1];
    const float* ftW  = (const float*)d_in[2];
    const float* ftb  = (const float*)d_in[3];
    const float* lng  = (const float*)d_in[4];
    const float* lnb  = (const float*)d_in[5];
    const float* W1   = (const float*)d_in[6];
    const float* as1  = (const float*)d_in[7];
    const float* ad1  = (const float*)d_in[8];
    const float* b1   = (const float*)d_in[9];
    const float* bng  = (const float*)d_in[10];
    const float* bnb  = (const float*)d_in[11];
    const float* bnm  = (const float*)d_in[12];
    const float* bnv  = (const float*)d_in[13];
    const float* W2   = (const float*)d_in[14];
    const float* as2  = (const float*)d_in[15];
    const float* ad2  = (const float*)d_in[16];
    const float* b2   = (const float*)d_in[17];
    float* out = (float*)d_out;

    // workspace layout (float units)
    float* F = (float*)d_ws;
    float* h1    = F;                        // 5,128,192  (10016 x 512)
    float* hpre  = F + 5128192;              // 5,128,192  (aliased as h2 later)
    float* h2    = hpre;
    float* aS1   = F + 10256384;             // 80,000
    float* aD1   = F + 10336384;             // 80,000
    float* gbuf  = F + 10416384;             // 160,000
    float* aS2   = F + 10576384;             // 80,000
    float* aD2   = F + 10656384;             // 80,000
    __hip_bfloat16* h0hi   = (__hip_bfloat16*)(F + 10736384);  // 5,128,192 bf16
    __hip_bfloat16* h0lo   = (__hip_bfloat16*)(F + 13300480);
    __hip_bfloat16* xhi    = (__hip_bfloat16*)(F + 15864576);  // 1,280,000 bf16
    __hip_bfloat16* xlo    = (__hip_bfloat16*)(F + 16504576);
    __hip_bfloat16* ftWThi = (__hip_bfloat16*)(F + 17144576);  // 65,536 bf16
    __hip_bfloat16* ftWTlo = (__hip_bfloat16*)(F + 17177344);
    __hip_bfloat16* W1Thi  = (__hip_bfloat16*)(F + 17210112);  // 262,144 bf16
    __hip_bfloat16* W1Tlo  = (__hip_bfloat16*)(F + 17341184);
    int* I = (int*)(F + 17472256);
    int* cnt    = I;
    int* off    = I + 10000;
    int* cursor = I + 20001;
    int* csrc   = I + 30001;                 // end ~17,662,257 f = 70.6 MB

    // CSR build
    k_zero<<<40, 256, 0, stream>>>(cnt, cursor);
    k_count<<<(N_EDGES + 255) / 256, 256, 0, stream>>>(ei, cnt);
    k_scan<<<1, 256, 0, stream>>>(cnt, off);
    k_scatter<<<(N_EDGES + 255) / 256, 256, 0, stream>>>(ei, off, cursor, csrc);

    // input / weight split conversions
    k_cvtx<<<(N_NODES * DIN + 255) / 256, 256, 0, stream>>>(x, xhi, xlo, N_NODES * DIN);
    k_cvtT<<<(DIN * DW + 255) / 256, 256, 0, stream>>>(ftW, ftWThi, ftWTlo, DIN);
    k_cvtT<<<(DW * DW + 255) / 256, 256, 0, stream>>>(W1, W1Thi, W1Tlo, DW);

    dim3 gg((N_NODES + 127) / 128, DW / 256);
    // ft GEMM: hpre = x @ ftW
    k_mgemm<DIN><<<gg, 256, 0, stream>>>(xhi, xlo, ftWThi, ftWTlo, hpre, N_NODES);
    // LN + leaky + bf16 split
    k_ln<<<N_NODES, 256, 0, stream>>>(hpre, ftb, lng, lnb, h0hi, h0lo);
    // GEMM1: h1 = h0 @ W1
    k_mgemm<DW><<<gg, 256, 0, stream>>>(h0hi, h0lo, W1Thi, W1Tlo, h1, N_NODES);

    k_att1<<<(N_NODES * NHEAD) / 4, 256, 0, stream>>>(h1, as1, ad1, aS1, aD1);
    k_agg1csr<<<N_NODES, 256, 0, stream>>>(csrc, off, h1, aS1, aD1, b1, bnm, bnv, bng, bnb, h2);
    k_gemm2<<<N_NODES / 16, 256, 0, stream>>>(h2, W2, gbuf);
    k_att2<<<(N_NODES * NHEAD + 255) / 256, 256, 0, stream>>>(gbuf, as2, ad2, aS2, aD2);
    k_agg2csr<<<(N_NODES + 3) / 4, 256, 0, stream>>>(csrc, off, gbuf, aS2, aD2, b2, out);
}

// Round 4
// 204.850 us; speedup vs baseline: 2.5881x; 1.2539x over previous
//
#include <hip/hip_runtime.h>
#include <hip/hip_bf16.h>
#include <math.h>

#define N_NODES 10000
#define N_EDGES 160000
#define DIN 128
#define DW 512
#define NHEAD 8
#define NC 64
#define MPAD 10016

typedef unsigned short ushort_t;
typedef __attribute__((ext_vector_type(8))) short bf16x8;
typedef __attribute__((ext_vector_type(4))) float f32x4;
typedef __attribute__((ext_vector_type(4))) unsigned int u32x4;

__device__ inline ushort_t f2bf(float v) {
    unsigned u = __builtin_bit_cast(unsigned, v);
    return (ushort_t)((u + 0x7fff + ((u >> 16) & 1)) >> 16);
}
__device__ inline float bf2f(ushort_t h) {
    return __builtin_bit_cast(float, (unsigned)h << 16);
}

// ================= CSR build =================
__global__ void k_zero(int* __restrict__ cnt, int* __restrict__ cursor) {
    int i = blockIdx.x * 256 + threadIdx.x;
    if (i < N_NODES) { cnt[i] = 0; cursor[i] = 0; }
}

__global__ void k_count(const int* __restrict__ ei, int* __restrict__ cnt) {
    int e = blockIdx.x * 256 + threadIdx.x;
    if (e < N_EDGES) atomicAdd(&cnt[ei[N_EDGES + e]], 1);
}

__global__ __launch_bounds__(256) void k_scan(const int* __restrict__ cnt, int* __restrict__ off) {
    __shared__ int ps[256];
    int t = threadIdx.x;
    int base = t * 40;
    int loc[40];
    int s = 0;
    #pragma unroll
    for (int i = 0; i < 40; i++) {
        int idx = base + i;
        int v = idx < N_NODES ? cnt[idx] : 0;
        loc[i] = s; s += v;
    }
    ps[t] = s; __syncthreads();
    for (int o = 1; o < 256; o <<= 1) {
        int v = (t >= o) ? ps[t - o] : 0;
        __syncthreads();
        ps[t] += v;
        __syncthreads();
    }
    int pre = (t > 0) ? ps[t - 1] : 0;
    #pragma unroll
    for (int i = 0; i < 40; i++) {
        int idx = base + i;
        if (idx < N_NODES) off[idx] = pre + loc[i];
    }
    if (t == 255) off[N_NODES] = ps[255];
}

__global__ void k_scatter(const int* __restrict__ ei, const int* __restrict__ off,
                          int* __restrict__ cursor, int* __restrict__ csrc) {
    int e = blockIdx.x * 256 + threadIdx.x;
    if (e < N_EDGES) {
        int d = ei[N_EDGES + e];
        int p = off[d] + atomicAdd(&cursor[d], 1);
        csrc[p] = ei[e];
    }
}

// ================= split-K' operand builders =================
// Ax[MPAD][384] = [hi(x) | lo(x) | hi(x)]   (pad rows zero)
__global__ void k_prepx(const float* __restrict__ x, ushort_t* __restrict__ Ax) {
    int i = blockIdx.x * 256 + threadIdx.x;
    if (i >= MPAD * DIN) return;
    int n = i >> 7, k = i & 127;
    float v = (n < N_NODES) ? x[n * DIN + k] : 0.f;
    ushort_t h = f2bf(v);
    ushort_t l = f2bf(v - bf2f(h));
    ushort_t* row = Ax + (size_t)n * 384;
    row[k] = h; row[128 + k] = l; row[256 + k] = h;
}

// Bx[512][384] = per col n: [hi(W) | hi(W) | lo(W)]  from ftW[128][512]
__global__ void k_prepWft(const float* __restrict__ W, ushort_t* __restrict__ Bx) {
    int i = blockIdx.x * 256 + threadIdx.x;
    if (i >= DIN * DW) return;
    int k = i >> 9, n = i & 511;
    float v = W[i];
    ushort_t h = f2bf(v);
    ushort_t l = f2bf(v - bf2f(h));
    ushort_t* row = Bx + (size_t)n * 384;
    row[k] = h; row[128 + k] = h; row[256 + k] = l;
}

// B1[512][1536] = per col n: [hi | hi | lo] from W1[512][512]
__global__ void k_prepW1(const float* __restrict__ W, ushort_t* __restrict__ B1) {
    int i = blockIdx.x * 256 + threadIdx.x;
    if (i >= DW * DW) return;
    int k = i >> 9, n = i & 511;
    float v = W[i];
    ushort_t h = f2bf(v);
    ushort_t l = f2bf(v - bf2f(h));
    ushort_t* row = B1 + (size_t)n * 1536;
    row[k] = h; row[512 + k] = h; row[1024 + k] = l;
}

// ================= LDS-staged bf16 MFMA GEMM =================
// C[MPAD][512] = A[MPAD][KP] @ B[512][KP]^T, tiles 128x128, BK=64, 4 waves (each 64x64 = 4x4 frags)
// XOR-swizzled LDS (byte ^ (row&7)<<4) kills the 16-way ds_read_b128 bank conflict.
template<int KT, int KP>
__global__ __launch_bounds__(256) void k_tgemm(const ushort_t* __restrict__ A,
                                               const ushort_t* __restrict__ B,
                                               float* __restrict__ C) {
    __shared__ ushort_t As[128 * 64];
    __shared__ ushort_t Bs[128 * 64];
    int t = threadIdx.x, w = t >> 6, l = t & 63;
    int lm = l & 15, g = l >> 4;
    int wr = w >> 1, wc = w & 1;
    int rowbase = blockIdx.x * 128;
    int colbase = blockIdx.y * 128;

    int srow = t >> 1;                      // tile row this thread stages (2 threads/row)
    int sb0 = (t & 1) * 64;                 // byte col base within 128B row
    int growA = min(rowbase + srow, MPAD - 1);
    const char* gA = (const char*)(A + (size_t)growA * KP) + sb0;
    const char* gB = (const char*)(B + (size_t)(colbase + srow) * KP) + sb0;
    char* lA = (char*)As + srow * 128;
    char* lB = (char*)Bs + srow * 128;
    int sw = (srow & 7) << 4;

    f32x4 acc[4][4];
    #pragma unroll
    for (int r = 0; r < 4; r++)
        #pragma unroll
        for (int c = 0; c < 4; c++) acc[r][c] = (f32x4){0.f, 0.f, 0.f, 0.f};

    u32x4 va[4], vb[4];
    #pragma unroll
    for (int j = 0; j < 4; ++j) {
        va[j] = *(const u32x4*)(gA + j * 16);
        vb[j] = *(const u32x4*)(gB + j * 16);
    }

    for (int kt = 0; kt < KT; ++kt) {
        __syncthreads();                    // previous iteration's readers done
        #pragma unroll
        for (int j = 0; j < 4; ++j) {
            *(u32x4*)(lA + ((sb0 + j * 16) ^ sw)) = va[j];
            *(u32x4*)(lB + ((sb0 + j * 16) ^ sw)) = vb[j];
        }
        __syncthreads();
        if (kt + 1 < KT) {                  // async-stage: issue next loads before MFMA
            #pragma unroll
            for (int j = 0; j < 4; ++j) {
                va[j] = *(const u32x4*)(gA + (size_t)(kt + 1) * 128 + j * 16);
                vb[j] = *(const u32x4*)(gB + (size_t)(kt + 1) * 128 + j * 16);
            }
        }
        #pragma unroll
        for (int ks = 0; ks < 2; ++ks) {
            bf16x8 af[4], bfr[4];
            #pragma unroll
            for (int r = 0; r < 4; ++r) {
                int row = wr * 64 + r * 16 + lm;
                af[r] = *(const bf16x8*)((const char*)As + row * 128 +
                                         ((ks * 64 + g * 16) ^ ((row & 7) << 4)));
            }
            #pragma unroll
            for (int c = 0; c < 4; ++c) {
                int col = wc * 64 + c * 16 + lm;
                bfr[c] = *(const bf16x8*)((const char*)Bs + col * 128 +
                                          ((ks * 64 + g * 16) ^ ((col & 7) << 4)));
            }
            #pragma unroll
            for (int r = 0; r < 4; ++r)
                #pragma unroll
                for (int c = 0; c < 4; ++c)
                    acc[r][c] = __builtin_amdgcn_mfma_f32_16x16x32_bf16(af[r], bfr[c], acc[r][c], 0, 0, 0);
        }
    }
    // C/D map: col = lane&15, row = (lane>>4)*4 + q
    #pragma unroll
    for (int r = 0; r < 4; ++r) {
        int row0 = rowbase + wr * 64 + r * 16 + g * 4;
        #pragma unroll
        for (int c = 0; c < 4; ++c) {
            int col = colbase + wc * 64 + c * 16 + lm;
            #pragma unroll
            for (int q = 0; q < 4; ++q)
                if (row0 + q < MPAD) C[(size_t)(row0 + q) * DW + col] = acc[r][c][q];
        }
    }
}

// ================= LN epilogue -> h0big[MPAD][1536] = [hi | lo | hi] =================
__global__ __launch_bounds__(256) void k_ln(const float* __restrict__ hpre,
                                            const float* __restrict__ fb,
                                            const float* __restrict__ g,
                                            const float* __restrict__ beta,
                                            ushort_t* __restrict__ h0big) {
    int n = blockIdx.x, t = threadIdx.x;
    ushort_t* row = h0big + (size_t)n * 1536;
    if (n >= N_NODES) {
        for (int j = t; j < 1536; j += 256) row[j] = 0;
        return;
    }
    __shared__ float red[8];
    float a0 = hpre[(size_t)n * DW + t] + fb[t];
    float a1 = hpre[(size_t)n * DW + t + 256] + fb[t + 256];
    float s = a0 + a1, sq = a0 * a0 + a1 * a1;
    for (int o = 32; o > 0; o >>= 1) { s += __shfl_down(s, o, 64); sq += __shfl_down(sq, o, 64); }
    int wid = t >> 6;
    if ((t & 63) == 0) { red[wid] = s; red[4 + wid] = sq; }
    __syncthreads();
    if (t == 0) {
        float ts = red[0] + red[1] + red[2] + red[3];
        float tq = red[4] + red[5] + red[6] + red[7];
        float mu = ts / DW;
        float var = tq / DW - mu * mu;
        red[0] = mu; red[1] = rsqrtf(var + 1e-5f);
    }
    __syncthreads();
    float mu = red[0], rs = red[1];
    float v0 = (a0 - mu) * rs * g[t] + beta[t];
    float v1 = (a1 - mu) * rs * g[t + 256] + beta[t + 256];
    v0 = v0 >= 0.f ? v0 : 0.2f * v0;
    v1 = v1 >= 0.f ? v1 : 0.2f * v1;
    ushort_t h0_ = f2bf(v0), l0_ = f2bf(v0 - bf2f(h0_));
    ushort_t h1_ = f2bf(v1), l1_ = f2bf(v1 - bf2f(h1_));
    row[t] = h0_;        row[512 + t] = l0_;        row[1024 + t] = h0_;
    row[256 + t] = h1_;  row[768 + t] = l1_;        row[1280 + t] = h1_;
}

// ================= attention dots layer 1 =================
__global__ __launch_bounds__(256) void k_att1(const float* __restrict__ h1,
                                              const float* __restrict__ asrc,
                                              const float* __restrict__ adst,
                                              float* __restrict__ a_s,
                                              float* __restrict__ a_d) {
    int t = threadIdx.x;
    int wid = t >> 6, lane = t & 63;
    int idx = blockIdx.x * 4 + wid;      // n*NHEAD + h
    if (idx >= N_NODES * NHEAD) return;
    int n = idx >> 3, h = idx & 7;
    float hv = h1[(size_t)n * DW + h * NC + lane];
    float vs = hv * asrc[h * NC + lane];
    float vd = hv * adst[h * NC + lane];
    for (int o = 32; o > 0; o >>= 1) { vs += __shfl_down(vs, o, 64); vd += __shfl_down(vd, o, 64); }
    if (lane == 0) { a_s[idx] = vs; a_d[idx] = vd; }
}

// ================= layer-1 aggregation, CSR, fused softmax + bias + BN + ReLU =================
__global__ __launch_bounds__(256) void k_agg1csr(
    const int* __restrict__ csrc, const int* __restrict__ off,
    const float* __restrict__ h1,
    const float* __restrict__ aS, const float* __restrict__ aD,
    const float* __restrict__ b1, const float* __restrict__ bnm,
    const float* __restrict__ bnv, const float* __restrict__ bng,
    const float* __restrict__ bnb, float* __restrict__ h2)
{
    int n = blockIdx.x, t = threadIdx.x;
    int beg = off[n], end = off[n + 1];
    __shared__ float wls[64][NHEAD];
    __shared__ int   sls[64];
    __shared__ float aDn[NHEAD];
    __shared__ float dsum[NHEAD];
    if (t < NHEAD) { aDn[t] = aD[n * NHEAD + t]; dsum[t] = 0.f; }
    __syncthreads();
    float acc0 = 0.f, acc1 = 0.f, dpart = 0.f;
    int hA = t >> 6, hB = 4 + (t >> 6);
    for (int c = beg; c < end; c += 64) {
        int m = min(64, end - c);
        if (t < m) sls[t] = csrc[c + t];
        __syncthreads();
        for (int idx = t; idx < m * NHEAD; idx += 256) {
            int el = idx >> 3, h = idx & 7;
            float l = aS[sls[el] * NHEAD + h] + aDn[h];
            l = l >= 0.f ? l : 0.2f * l;
            float w = __expf(l);
            wls[el][h] = w;
            dpart += w;
        }
        __syncthreads();
        for (int el = 0; el < m; el++) {
            const float* hr = h1 + (size_t)sls[el] * DW;
            acc0 += wls[el][hA] * hr[t];
            acc1 += wls[el][hB] * hr[t + 256];
        }
        __syncthreads();
    }
    for (int o = 8; o < 64; o <<= 1) dpart += __shfl_down(dpart, o, 64);
    if ((t & 63) < NHEAD) atomicAdd(&dsum[t & 7], dpart);
    __syncthreads();
    float rdA = dsum[hA] > 0.f ? 1.f / dsum[hA] : 0.f;
    float rdB = dsum[hB] > 0.f ? 1.f / dsum[hB] : 0.f;
    int j0 = t, j1 = t + 256;
    float v0 = acc0 * rdA + b1[j0];
    v0 = (v0 - bnm[j0]) * rsqrtf(bnv[j0] + 1e-5f) * bng[j0] + bnb[j0];
    v0 = v0 > 0.f ? v0 : 0.f;
    float v1 = acc1 * rdB + b1[j1];
    v1 = (v1 - bnm[j1]) * rsqrtf(bnv[j1] + 1e-5f) * bng[j1] + bnb[j1];
    v1 = v1 > 0.f ? v1 : 0.f;
    h2[(size_t)n * DW + j0] = v0;
    h2[(size_t)n * DW + j1] = v1;
}

// ================= GEMM2: g = h2 @ W2 [512,16] =================
__global__ __launch_bounds__(256) void k_gemm2(const float* __restrict__ h2,
                                               const float* __restrict__ W2,
                                               float* __restrict__ gout) {
    __shared__ float Ws[DW * 16];
    int t = threadIdx.x;
    for (int i = t; i < DW * 16; i += 256) Ws[i] = W2[i];
    __syncthreads();
    int nb = blockIdx.x * 16;
    int nl = t >> 4, j = t & 15;
    const float* hr = h2 + (size_t)(nb + nl) * DW;
    float acc = 0.f;
    for (int k = 0; k < DW; k++) acc += hr[k] * Ws[k * 16 + j];
    gout[(nb + nl) * 16 + j] = acc;
}

// ================= attention dots layer 2 =================
__global__ void k_att2(const float* __restrict__ gout, const float* __restrict__ as2,
                       const float* __restrict__ ad2, float* __restrict__ a_s,
                       float* __restrict__ a_d) {
    int idx = blockIdx.x * 256 + threadIdx.x;
    if (idx >= N_NODES * NHEAD) return;
    int n = idx >> 3, h = idx & 7;
    float g0 = gout[n * 16 + 2 * h], g1 = gout[n * 16 + 2 * h + 1];
    a_s[idx] = g0 * as2[2 * h] + g1 * as2[2 * h + 1];
    a_d[idx] = g0 * ad2[2 * h] + g1 * ad2[2 * h + 1];
}

// ================= layer-2 aggregation, CSR, fused head-mean + b2 =================
__global__ __launch_bounds__(256) void k_agg2csr(
    const int* __restrict__ csrc, const int* __restrict__ off,
    const float* __restrict__ gbuf,
    const float* __restrict__ aS, const float* __restrict__ aD,
    const float* __restrict__ b2, float* __restrict__ outp)
{
    int t = threadIdx.x;
    int n = blockIdx.x * 4 + (t >> 6);
    int lane = t & 63;
    if (n >= N_NODES) return;
    int beg = off[n], end = off[n + 1];
    int j = lane & 15, slot = lane >> 4, h = j >> 1;
    float adn = aD[n * NHEAD + h];
    float acc = 0.f, den = 0.f;
    for (int c = beg + slot; c < end; c += 4) {
        int s = csrc[c];
        float l = aS[s * NHEAD + h] + adn;
        l = l >= 0.f ? l : 0.2f * l;
        float w = __expf(l);
        den += w;
        acc += w * gbuf[s * 16 + j];
    }
    acc += __shfl_down(acc, 16, 64); acc += __shfl_down(acc, 32, 64);
    den += __shfl_down(den, 16, 64); den += __shfl_down(den, 32, 64);
    float v = (lane < 16 && den > 0.f) ? acc / den : 0.f;
    v += __shfl_down(v, 2, 64);
    v += __shfl_down(v, 4, 64);
    v += __shfl_down(v, 8, 64);
    if (lane < 2) outp[n * 2 + lane] = v * 0.125f + b2[lane];
}

extern "C" void kernel_launch(void* const* d_in, const int* in_sizes, int n_in,
                              void* d_out, int out_size, void* d_ws, size_t ws_size,
                              hipStream_t stream) {
    const float* x    = (const float*)d_in[0];
    const int*   ei   = (const int*)d_in[1];
    const float* ftW  = (const float*)d_in[2];
    const float* ftb  = (const float*)d_in[3];
    const float* lng  = (const float*)d_in[4];
    const float* lnb  = (const float*)d_in[5];
    const float* W1   = (const float*)d_in[6];
    const float* as1  = (const float*)d_in[7];
    const float* ad1  = (const float*)d_in[8];
    const float* b1   = (const float*)d_in[9];
    const float* bng  = (const float*)d_in[10];
    const float* bnb  = (const float*)d_in[11];
    const float* bnm  = (const float*)d_in[12];
    const float* bnv  = (const float*)d_in[13];
    const float* W2   = (const float*)d_in[14];
    const float* as2  = (const float*)d_in[15];
    const float* ad2  = (const float*)d_in[16];
    const float* b2   = (const float*)d_in[17];
    float* out = (float*)d_out;

    // ---- workspace layout (float offsets), lifetime-aliased, total 73.1 MB ----
    float* F = (float*)d_ws;
    // region0 [0, 5,128,192): Ax+Bx+cnt+cursor (early) -> h1 (mid) -> gbuf (late)
    ushort_t* Ax   = (ushort_t*)(F + 0);           // 10016*384 us
    ushort_t* Bx   = (ushort_t*)(F + 1923072);     // 512*384 us
    int* cnt       = (int*)(F + 2021376);
    int* cursor    = (int*)(F + 2031376);
    float* h1      = F + 0;                        // 10016*512
    float* gbuf    = F + 0;                        // 160,000 (after h1 dead)
    // region1 [5,128,192, 10,256,384): hpre (early) -> B1 (mid) -> h2 (late)
    float* hpre    = F + 5128192;
    ushort_t* B1   = (ushort_t*)(F + 5128192);     // 512*1536 us (after k_ln)
    float* h2      = F + 5128192;                  // (after GEMM1)
    float* aS1     = F + 10256384;                 // 80,000 (reused as aS2)
    float* aD1     = F + 10336384;                 // 80,000 (reused as aD2)
    ushort_t* h0big = (ushort_t*)(F + 10416384);   // 10016*1536 us = 7,692,288 f
    int* off       = (int*)(F + 18108672);         // 10,001
    int* csrc      = (int*)(F + 18118673);         // 160,000 -> end 18,278,673 f

    // CSR build
    k_zero<<<40, 256, 0, stream>>>(cnt, cursor);
    k_count<<<(N_EDGES + 255) / 256, 256, 0, stream>>>(ei, cnt);
    k_scan<<<1, 256, 0, stream>>>(cnt, off);
    k_scatter<<<(N_EDGES + 255) / 256, 256, 0, stream>>>(ei, off, cursor, csrc);

    // operand prep + ft GEMM
    k_prepx<<<(MPAD * DIN + 255) / 256, 256, 0, stream>>>(x, Ax);
    k_prepWft<<<(DIN * DW + 255) / 256, 256, 0, stream>>>(ftW, Bx);
    dim3 gg((MPAD + 127) / 128, DW / 128);
    k_tgemm<6, 384><<<gg, 256, 0, stream>>>(Ax, Bx, hpre);
    k_ln<<<MPAD, 256, 0, stream>>>(hpre, ftb, lng, lnb, h0big);
    k_prepW1<<<(DW * DW + 255) / 256, 256, 0, stream>>>(W1, B1);   // hpre dead now
    k_tgemm<24, 1536><<<gg, 256, 0, stream>>>(h0big, B1, h1);

    k_att1<<<(N_NODES * NHEAD) / 4, 256, 0, stream>>>(h1, as1, ad1, aS1, aD1);
    k_agg1csr<<<N_NODES, 256, 0, stream>>>(csrc, off, h1, aS1, aD1, b1, bnm, bnv, bng, bnb, h2);
    k_gemm2<<<N_NODES / 16, 256, 0, stream>>>(h2, W2, gbuf);       // h1 dead now
    k_att2<<<(N_NODES * NHEAD + 255) / 256, 256, 0, stream>>>(gbuf, as2, ad2, aS1, aD1);
    k_agg2csr<<<(N_NODES + 3) / 4, 256, 0, stream>>>(csrc, off, gbuf, aS1, aD1, b2, out);
}

// Round 5
// 182.312 us; speedup vs baseline: 2.9081x; 1.1236x over previous
//
#include <hip/hip_runtime.h>
#include <hip/hip_bf16.h>
#include <math.h>

#define N_NODES 10000
#define N_EDGES 160000
#define DIN 128
#define DW 512
#define NHEAD 8
#define NC 64
#define MPAD 10016

typedef unsigned short ushort_t;
typedef __attribute__((ext_vector_type(8))) short bf16x8;
typedef __attribute__((ext_vector_type(4))) float f32x4;
typedef __attribute__((ext_vector_type(4))) unsigned int u32x4;

__device__ inline ushort_t f2bf(float v) {
    unsigned u = __builtin_bit_cast(unsigned, v);
    return (ushort_t)((u + 0x7fff + ((u >> 16) & 1)) >> 16);
}
__device__ inline float bf2f(ushort_t h) {
    return __builtin_bit_cast(float, (unsigned)h << 16);
}

// ================= CSR build =================
__global__ void k_zero(int* __restrict__ cnt, int* __restrict__ cursor) {
    int i = blockIdx.x * 256 + threadIdx.x;
    if (i < N_NODES) { cnt[i] = 0; cursor[i] = 0; }
}

__global__ void k_count(const int* __restrict__ ei, int* __restrict__ cnt) {
    int e = blockIdx.x * 256 + threadIdx.x;
    if (e < N_EDGES) atomicAdd(&cnt[ei[N_EDGES + e]], 1);
}

__global__ __launch_bounds__(256) void k_scan(const int* __restrict__ cnt, int* __restrict__ off) {
    __shared__ int ps[256];
    int t = threadIdx.x;
    int base = t * 40;
    int loc[40];
    int s = 0;
    #pragma unroll
    for (int i = 0; i < 40; i++) {
        int idx = base + i;
        int v = idx < N_NODES ? cnt[idx] : 0;
        loc[i] = s; s += v;
    }
    ps[t] = s; __syncthreads();
    for (int o = 1; o < 256; o <<= 1) {
        int v = (t >= o) ? ps[t - o] : 0;
        __syncthreads();
        ps[t] += v;
        __syncthreads();
    }
    int pre = (t > 0) ? ps[t - 1] : 0;
    #pragma unroll
    for (int i = 0; i < 40; i++) {
        int idx = base + i;
        if (idx < N_NODES) off[idx] = pre + loc[i];
    }
    if (t == 255) off[N_NODES] = ps[255];
}

__global__ void k_scatter(const int* __restrict__ ei, const int* __restrict__ off,
                          int* __restrict__ cursor, int* __restrict__ csrc) {
    int e = blockIdx.x * 256 + threadIdx.x;
    if (e < N_EDGES) {
        int d = ei[N_EDGES + e];
        int p = off[d] + atomicAdd(&cursor[d], 1);
        csrc[p] = ei[e];
    }
}

// ================= split-K' operand builders =================
__global__ void k_prepx(const float* __restrict__ x, ushort_t* __restrict__ Ax) {
    int i = blockIdx.x * 256 + threadIdx.x;
    if (i >= MPAD * DIN) return;
    int n = i >> 7, k = i & 127;
    float v = (n < N_NODES) ? x[n * DIN + k] : 0.f;
    ushort_t h = f2bf(v);
    ushort_t l = f2bf(v - bf2f(h));
    ushort_t* row = Ax + (size_t)n * 384;
    row[k] = h; row[128 + k] = l; row[256 + k] = h;
}

__global__ void k_prepWft(const float* __restrict__ W, ushort_t* __restrict__ Bx) {
    int i = blockIdx.x * 256 + threadIdx.x;
    if (i >= DIN * DW) return;
    int k = i >> 9, n = i & 511;
    float v = W[i];
    ushort_t h = f2bf(v);
    ushort_t l = f2bf(v - bf2f(h));
    ushort_t* row = Bx + (size_t)n * 384;
    row[k] = h; row[128 + k] = h; row[256 + k] = l;
}

__global__ void k_prepW1(const float* __restrict__ W, ushort_t* __restrict__ B1) {
    int i = blockIdx.x * 256 + threadIdx.x;
    if (i >= DW * DW) return;
    int k = i >> 9, n = i & 511;
    float v = W[i];
    ushort_t h = f2bf(v);
    ushort_t l = f2bf(v - bf2f(h));
    ushort_t* row = B1 + (size_t)n * 1536;
    row[k] = h; row[512 + k] = h; row[1024 + k] = l;
}

// ================= LDS-staged bf16 MFMA GEMM =================
// C = A[MPAD][KP] @ B[512][KP]^T, tiles 128x128, BK=64, 4 waves (each 64x64).
// ATT=1: store C as bf16 to Cb AND fuse the attention dots (wave's 64-col window
//        = exactly one head) -> aS/aD; ATT=0: store f32 to C.
template<int KT, int KP, bool ATT>
__global__ __launch_bounds__(256) void k_tgemm(const ushort_t* __restrict__ A,
                                               const ushort_t* __restrict__ B,
                                               float* __restrict__ C,
                                               ushort_t* __restrict__ Cb,
                                               const float* __restrict__ asrc,
                                               const float* __restrict__ adst,
                                               float* __restrict__ aS,
                                               float* __restrict__ aD) {
    __shared__ ushort_t As[128 * 64];
    __shared__ ushort_t Bs[128 * 64];
    int t = threadIdx.x, w = t >> 6, l = t & 63;
    int lm = l & 15, g = l >> 4;
    int wr = w >> 1, wc = w & 1;
    int rowbase = blockIdx.x * 128;
    int colbase = blockIdx.y * 128;

    int srow = t >> 1;
    int sb0 = (t & 1) * 64;
    int growA = min(rowbase + srow, MPAD - 1);
    const char* gA = (const char*)(A + (size_t)growA * KP) + sb0;
    const char* gB = (const char*)(B + (size_t)(colbase + srow) * KP) + sb0;
    char* lA = (char*)As + srow * 128;
    char* lB = (char*)Bs + srow * 128;
    int sw = (srow & 7) << 4;

    f32x4 acc[4][4];
    #pragma unroll
    for (int r = 0; r < 4; r++)
        #pragma unroll
        for (int c = 0; c < 4; c++) acc[r][c] = (f32x4){0.f, 0.f, 0.f, 0.f};

    u32x4 va[4], vb[4];
    #pragma unroll
    for (int j = 0; j < 4; ++j) {
        va[j] = *(const u32x4*)(gA + j * 16);
        vb[j] = *(const u32x4*)(gB + j * 16);
    }

    for (int kt = 0; kt < KT; ++kt) {
        __syncthreads();
        #pragma unroll
        for (int j = 0; j < 4; ++j) {
            *(u32x4*)(lA + ((sb0 + j * 16) ^ sw)) = va[j];
            *(u32x4*)(lB + ((sb0 + j * 16) ^ sw)) = vb[j];
        }
        __syncthreads();
        if (kt + 1 < KT) {
            #pragma unroll
            for (int j = 0; j < 4; ++j) {
                va[j] = *(const u32x4*)(gA + (size_t)(kt + 1) * 128 + j * 16);
                vb[j] = *(const u32x4*)(gB + (size_t)(kt + 1) * 128 + j * 16);
            }
        }
        #pragma unroll
        for (int ks = 0; ks < 2; ++ks) {
            bf16x8 af[4], bfr[4];
            #pragma unroll
            for (int r = 0; r < 4; ++r) {
                int row = wr * 64 + r * 16 + lm;
                af[r] = *(const bf16x8*)((const char*)As + row * 128 +
                                         ((ks * 64 + g * 16) ^ ((row & 7) << 4)));
            }
            #pragma unroll
            for (int c = 0; c < 4; ++c) {
                int col = wc * 64 + c * 16 + lm;
                bfr[c] = *(const bf16x8*)((const char*)Bs + col * 128 +
                                          ((ks * 64 + g * 16) ^ ((col & 7) << 4)));
            }
            #pragma unroll
            for (int r = 0; r < 4; ++r)
                #pragma unroll
                for (int c = 0; c < 4; ++c)
                    acc[r][c] = __builtin_amdgcn_mfma_f32_16x16x32_bf16(af[r], bfr[c], acc[r][c], 0, 0, 0);
        }
    }
    // C/D map: col = lane&15, row = (lane>>4)*4 + q
    if (!ATT) {
        #pragma unroll
        for (int r = 0; r < 4; ++r) {
            int row0 = rowbase + wr * 64 + r * 16 + g * 4;
            #pragma unroll
            for (int c = 0; c < 4; ++c) {
                int col = colbase + wc * 64 + c * 16 + lm;
                #pragma unroll
                for (int q = 0; q < 4; ++q)
                    if (row0 + q < MPAD) C[(size_t)(row0 + q) * DW + col] = acc[r][c][q];
            }
        }
    } else {
        int h = 2 * blockIdx.y + wc;                  // this wave's head
        float asv[4], adv[4];
        #pragma unroll
        for (int c = 0; c < 4; ++c) {
            asv[c] = asrc[h * NC + c * 16 + lm];
            adv[c] = adst[h * NC + c * 16 + lm];
        }
        #pragma unroll
        for (int r = 0; r < 4; ++r) {
            int row0 = rowbase + wr * 64 + r * 16 + g * 4;
            #pragma unroll
            for (int c = 0; c < 4; ++c) {
                int col = colbase + wc * 64 + c * 16 + lm;
                #pragma unroll
                for (int q = 0; q < 4; ++q)
                    if (row0 + q < MPAD) Cb[(size_t)(row0 + q) * DW + col] = f2bf(acc[r][c][q]);
            }
            #pragma unroll
            for (int q = 0; q < 4; ++q) {
                float ss = acc[r][0][q] * asv[0] + acc[r][1][q] * asv[1] +
                           acc[r][2][q] * asv[2] + acc[r][3][q] * asv[3];
                float dd = acc[r][0][q] * adv[0] + acc[r][1][q] * adv[1] +
                           acc[r][2][q] * adv[2] + acc[r][3][q] * adv[3];
                #pragma unroll
                for (int m = 1; m < 16; m <<= 1) {
                    ss += __shfl_xor(ss, m, 64);
                    dd += __shfl_xor(dd, m, 64);
                }
                int row = row0 + q;
                if (lm == 0 && row < N_NODES) {
                    aS[row * NHEAD + h] = ss;
                    aD[row * NHEAD + h] = dd;
                }
            }
        }
    }
}

// ================= LN epilogue -> h0big[MPAD][1536] = [hi | lo | hi] =================
__global__ __launch_bounds__(256) void k_ln(const float* __restrict__ hpre,
                                            const float* __restrict__ fb,
                                            const float* __restrict__ g,
                                            const float* __restrict__ beta,
                                            ushort_t* __restrict__ h0big) {
    int n = blockIdx.x, t = threadIdx.x;
    ushort_t* row = h0big + (size_t)n * 1536;
    if (n >= N_NODES) {
        for (int j = t; j < 1536; j += 256) row[j] = 0;
        return;
    }
    __shared__ float red[8];
    float a0 = hpre[(size_t)n * DW + t] + fb[t];
    float a1 = hpre[(size_t)n * DW + t + 256] + fb[t + 256];
    float s = a0 + a1, sq = a0 * a0 + a1 * a1;
    for (int o = 32; o > 0; o >>= 1) { s += __shfl_down(s, o, 64); sq += __shfl_down(sq, o, 64); }
    int wid = t >> 6;
    if ((t & 63) == 0) { red[wid] = s; red[4 + wid] = sq; }
    __syncthreads();
    if (t == 0) {
        float ts = red[0] + red[1] + red[2] + red[3];
        float tq = red[4] + red[5] + red[6] + red[7];
        float mu = ts / DW;
        float var = tq / DW - mu * mu;
        red[0] = mu; red[1] = rsqrtf(var + 1e-5f);
    }
    __syncthreads();
    float mu = red[0], rs = red[1];
    float v0 = (a0 - mu) * rs * g[t] + beta[t];
    float v1 = (a1 - mu) * rs * g[t + 256] + beta[t + 256];
    v0 = v0 >= 0.f ? v0 : 0.2f * v0;
    v1 = v1 >= 0.f ? v1 : 0.2f * v1;
    ushort_t h0_ = f2bf(v0), l0_ = f2bf(v0 - bf2f(h0_));
    ushort_t h1_ = f2bf(v1), l1_ = f2bf(v1 - bf2f(h1_));
    row[t] = h0_;        row[512 + t] = l0_;        row[1024 + t] = h0_;
    row[256 + t] = h1_;  row[768 + t] = l1_;        row[1280 + t] = h1_;
}

// ================= layer-1 aggregation: bf16 gather, fused softmax+bias+BN+ReLU -> bf16 h2 =================
__global__ __launch_bounds__(256) void k_agg1csr(
    const int* __restrict__ csrc, const int* __restrict__ off,
    const ushort_t* __restrict__ h1b,
    const float* __restrict__ aS, const float* __restrict__ aD,
    const float* __restrict__ b1, const float* __restrict__ bnm,
    const float* __restrict__ bnv, const float* __restrict__ bng,
    const float* __restrict__ bnb, ushort_t* __restrict__ h2b)
{
    int n = blockIdx.x, t = threadIdx.x;
    int beg = off[n], end = off[n + 1];
    __shared__ float wls[64][NHEAD];
    __shared__ int   sls[64];
    __shared__ float aDn[NHEAD];
    __shared__ float dsum[NHEAD];
    if (t < NHEAD) { aDn[t] = aD[n * NHEAD + t]; dsum[t] = 0.f; }
    __syncthreads();
    float acc0 = 0.f, acc1 = 0.f, dpart = 0.f;
    int hA = t >> 5;                       // head of cols 2t, 2t+1
    for (int c = beg; c < end; c += 64) {
        int m = min(64, end - c);
        if (t < m) sls[t] = csrc[c + t];
        __syncthreads();
        for (int idx = t; idx < m * NHEAD; idx += 256) {
            int el = idx >> 3, h = idx & 7;
            float l = aS[sls[el] * NHEAD + h] + aDn[h];
            l = l >= 0.f ? l : 0.2f * l;
            float w = __expf(l);
            wls[el][h] = w;
            dpart += w;
        }
        __syncthreads();
        for (int el = 0; el < m; el++) {
            float w = wls[el][hA];
            unsigned v = *(const unsigned*)(h1b + (size_t)sls[el] * DW + 2 * t);
            acc0 += w * __builtin_bit_cast(float, v << 16);
            acc1 += w * __builtin_bit_cast(float, v & 0xffff0000u);
        }
        __syncthreads();
    }
    for (int o = 8; o < 64; o <<= 1) dpart += __shfl_down(dpart, o, 64);
    if ((t & 63) < NHEAD) atomicAdd(&dsum[t & 7], dpart);
    __syncthreads();
    float rd = dsum[hA] > 0.f ? 1.f / dsum[hA] : 0.f;
    int j0 = 2 * t, j1 = 2 * t + 1;
    float v0 = acc0 * rd + b1[j0];
    v0 = (v0 - bnm[j0]) * rsqrtf(bnv[j0] + 1e-5f) * bng[j0] + bnb[j0];
    v0 = v0 > 0.f ? v0 : 0.f;
    float v1 = acc1 * rd + b1[j1];
    v1 = (v1 - bnm[j1]) * rsqrtf(bnv[j1] + 1e-5f) * bng[j1] + bnb[j1];
    v1 = v1 > 0.f ? v1 : 0.f;
    unsigned pk = (unsigned)f2bf(v0) | ((unsigned)f2bf(v1) << 16);
    *(unsigned*)(h2b + (size_t)n * DW + 2 * t) = pk;
}

// ================= GEMM2: g = h2(bf16) @ W2 [512,16] =================
__global__ __launch_bounds__(256) void k_gemm2(const ushort_t* __restrict__ h2b,
                                               const float* __restrict__ W2,
                                               float* __restrict__ gout) {
    __shared__ float Ws[DW * 16];
    int t = threadIdx.x;
    for (int i = t; i < DW * 16; i += 256) Ws[i] = W2[i];
    __syncthreads();
    int nb = blockIdx.x * 16;
    int nl = t >> 4, j = t & 15;
    const ushort_t* hr = h2b + (size_t)(nb + nl) * DW;
    float acc = 0.f;
    for (int k = 0; k < DW; k++) acc += bf2f(hr[k]) * Ws[k * 16 + j];
    gout[(nb + nl) * 16 + j] = acc;
}

// ================= attention dots layer 2 =================
__global__ void k_att2(const float* __restrict__ gout, const float* __restrict__ as2,
                       const float* __restrict__ ad2, float* __restrict__ a_s,
                       float* __restrict__ a_d) {
    int idx = blockIdx.x * 256 + threadIdx.x;
    if (idx >= N_NODES * NHEAD) return;
    int n = idx >> 3, h = idx & 7;
    float g0 = gout[n * 16 + 2 * h], g1 = gout[n * 16 + 2 * h + 1];
    a_s[idx] = g0 * as2[2 * h] + g1 * as2[2 * h + 1];
    a_d[idx] = g0 * ad2[2 * h] + g1 * ad2[2 * h + 1];
}

// ================= layer-2 aggregation, CSR, fused head-mean + b2 =================
__global__ __launch_bounds__(256) void k_agg2csr(
    const int* __restrict__ csrc, const int* __restrict__ off,
    const float* __restrict__ gbuf,
    const float* __restrict__ aS, const float* __restrict__ aD,
    const float* __restrict__ b2, float* __restrict__ outp)
{
    int t = threadIdx.x;
    int n = blockIdx.x * 4 + (t >> 6);
    int lane = t & 63;
    if (n >= N_NODES) return;
    int beg = off[n], end = off[n + 1];
    int j = lane & 15, slot = lane >> 4, h = j >> 1;
    float adn = aD[n * NHEAD + h];
    float acc = 0.f, den = 0.f;
    for (int c = beg + slot; c < end; c += 4) {
        int s = csrc[c];
        float l = aS[s * NHEAD + h] + adn;
        l = l >= 0.f ? l : 0.2f * l;
        float w = __expf(l);
        den += w;
        acc += w * gbuf[s * 16 + j];
    }
    acc += __shfl_down(acc, 16, 64); acc += __shfl_down(acc, 32, 64);
    den += __shfl_down(den, 16, 64); den += __shfl_down(den, 32, 64);
    float v = (lane < 16 && den > 0.f) ? acc / den : 0.f;
    v += __shfl_down(v, 2, 64);
    v += __shfl_down(v, 4, 64);
    v += __shfl_down(v, 8, 64);
    if (lane < 2) outp[n * 2 + lane] = v * 0.125f + b2[lane];
}

extern "C" void kernel_launch(void* const* d_in, const int* in_sizes, int n_in,
                              void* d_out, int out_size, void* d_ws, size_t ws_size,
                              hipStream_t stream) {
    const float* x    = (const float*)d_in[0];
    const int*   ei   = (const int*)d_in[1];
    const float* ftW  = (const float*)d_in[2];
    const float* ftb  = (const float*)d_in[3];
    const float* lng  = (const float*)d_in[4];
    const float* lnb  = (const float*)d_in[5];
    const float* W1   = (const float*)d_in[6];
    const float* as1  = (const float*)d_in[7];
    const float* ad1  = (const float*)d_in[8];
    const float* b1   = (const float*)d_in[9];
    const float* bng  = (const float*)d_in[10];
    const float* bnb  = (const float*)d_in[11];
    const float* bnm  = (const float*)d_in[12];
    const float* bnv  = (const float*)d_in[13];
    const float* W2   = (const float*)d_in[14];
    const float* as2  = (const float*)d_in[15];
    const float* ad2  = (const float*)d_in[16];
    const float* b2   = (const float*)d_in[17];
    float* out = (float*)d_out;

    // ---- workspace layout (float offsets), lifetime-aliased ----
    float* F = (float*)d_ws;
    // region0 [0, 5,128,192): {Ax,Bx,cnt,cursor} -> h1b (bf16) -> gbuf
    ushort_t* Ax   = (ushort_t*)(F + 0);
    ushort_t* Bx   = (ushort_t*)(F + 1923072);
    int* cnt       = (int*)(F + 2021376);
    int* cursor    = (int*)(F + 2031376);
    ushort_t* h1b  = (ushort_t*)(F + 0);           // MPAD*512 bf16 = 2,564,096 f
    float* gbuf    = F + 0;                        // 160,000 (after h1b dead)
    // region1 [5,128,192, ...): hpre -> B1 -> h2b
    float* hpre    = F + 5128192;
    ushort_t* B1   = (ushort_t*)(F + 5128192);
    ushort_t* h2b  = (ushort_t*)(F + 5128192);     // MPAD*512 bf16
    float* aS1     = F + 10256384;                 // 80,000 (reused layer 2)
    float* aD1     = F + 10336384;                 // 80,000
    ushort_t* h0big = (ushort_t*)(F + 10416384);   // MPAD*1536 bf16
    int* off       = (int*)(F + 18108672);
    int* csrc      = (int*)(F + 18118673);

    // CSR build
    k_zero<<<40, 256, 0, stream>>>(cnt, cursor);
    k_count<<<(N_EDGES + 255) / 256, 256, 0, stream>>>(ei, cnt);
    k_scan<<<1, 256, 0, stream>>>(cnt, off);
    k_scatter<<<(N_EDGES + 255) / 256, 256, 0, stream>>>(ei, off, cursor, csrc);

    // operand prep + ft GEMM + LN
    k_prepx<<<(MPAD * DIN + 255) / 256, 256, 0, stream>>>(x, Ax);
    k_prepWft<<<(DIN * DW + 255) / 256, 256, 0, stream>>>(ftW, Bx);
    dim3 gg((MPAD + 127) / 128, DW / 128);
    k_tgemm<6, 384, false><<<gg, 256, 0, stream>>>(Ax, Bx, hpre, nullptr, nullptr, nullptr, nullptr, nullptr);
    k_ln<<<MPAD, 256, 0, stream>>>(hpre, ftb, lng, lnb, h0big);
    k_prepW1<<<(DW * DW + 255) / 256, 256, 0, stream>>>(W1, B1);
    // GEMM1 with fused attention dots + bf16 output
    k_tgemm<24, 1536, true><<<gg, 256, 0, stream>>>(h0big, B1, nullptr, h1b, as1, ad1, aS1, aD1);

    k_agg1csr<<<N_NODES, 256, 0, stream>>>(csrc, off, h1b, aS1, aD1, b1, bnm, bnv, bng, bnb, h2b);
    k_gemm2<<<N_NODES / 16, 256, 0, stream>>>(h2b, W2, gbuf);      // h1b dead now
    k_att2<<<(N_NODES * NHEAD + 255) / 256, 256, 0, stream>>>(gbuf, as2, ad2, aS1, aD1);
    k_agg2csr<<<(N_NODES + 3) / 4, 256, 0, stream>>>(csrc, off, gbuf, aS1, aD1, b2, out);
}

// Round 6
// 170.357 us; speedup vs baseline: 3.1122x; 1.0702x over previous
//
#include <hip/hip_runtime.h>
#include <hip/hip_bf16.h>
#include <math.h>

#define N_NODES 10000
#define N_EDGES 160000
#define DIN 128
#define DW 512
#define NHEAD 8
#define NC 64
#define MPAD 10112   // 79 * 128

typedef unsigned short ushort_t;
typedef __attribute__((ext_vector_type(8))) short bf16x8;
typedef __attribute__((ext_vector_type(4))) float f32x4;

__device__ inline ushort_t f2bf(float v) {
    unsigned u = __builtin_bit_cast(unsigned, v);
    return (ushort_t)((u + 0x7fff + ((u >> 16) & 1)) >> 16);
}
__device__ inline float bf2f(ushort_t h) {
    return __builtin_bit_cast(float, (unsigned)h << 16);
}

// swizzled tile-major index: tiles of 128 rows x 64 k, 8192 ushort each.
// within tile: us = r*64 + (kc ^ ((r&7)<<3))  == byte ^ ((r&7)<<4)
__device__ __forceinline__ size_t swz_idx(int rb, int r, int kp, int nkt) {
    int kt = kp >> 6, kc = kp & 63;
    return ((size_t)(rb * nkt + kt)) * 8192 + r * 64 + (kc ^ ((r & 7) << 3));
}

__device__ __forceinline__ void gld16(const ushort_t* g, ushort_t* l) {
    __builtin_amdgcn_global_load_lds(
        (const __attribute__((address_space(1))) void*)g,
        (__attribute__((address_space(3))) void*)l, 16, 0, 0);
}

// ================= CSR build =================
__global__ void k_zero(int* __restrict__ cnt, int* __restrict__ cursor) {
    int i = blockIdx.x * 256 + threadIdx.x;
    if (i < N_NODES) { cnt[i] = 0; cursor[i] = 0; }
}

__global__ void k_count(const int* __restrict__ ei, int* __restrict__ cnt) {
    int e = blockIdx.x * 256 + threadIdx.x;
    if (e < N_EDGES) atomicAdd(&cnt[ei[N_EDGES + e]], 1);
}

__global__ __launch_bounds__(256) void k_scan(const int* __restrict__ cnt, int* __restrict__ off) {
    __shared__ int ps[256];
    int t = threadIdx.x;
    int base = t * 40;
    int loc[40];
    int s = 0;
    #pragma unroll
    for (int i = 0; i < 40; i++) {
        int idx = base + i;
        int v = idx < N_NODES ? cnt[idx] : 0;
        loc[i] = s; s += v;
    }
    ps[t] = s; __syncthreads();
    for (int o = 1; o < 256; o <<= 1) {
        int v = (t >= o) ? ps[t - o] : 0;
        __syncthreads();
        ps[t] += v;
        __syncthreads();
    }
    int pre = (t > 0) ? ps[t - 1] : 0;
    #pragma unroll
    for (int i = 0; i < 40; i++) {
        int idx = base + i;
        if (idx < N_NODES) off[idx] = pre + loc[i];
    }
    if (t == 255) off[N_NODES] = ps[255];
}

__global__ void k_scatter(const int* __restrict__ ei, const int* __restrict__ off,
                          int* __restrict__ cursor, int* __restrict__ csrc) {
    int e = blockIdx.x * 256 + threadIdx.x;
    if (e < N_EDGES) {
        int d = ei[N_EDGES + e];
        int p = off[d] + atomicAdd(&cursor[d], 1);
        csrc[p] = ei[e];
    }
}

// ================= operand builders (tile-major, pre-swizzled) =================
// Ax: rows=x nodes, K'=384 = [hi | lo | hi]
__global__ void k_prepx(const float* __restrict__ x, ushort_t* __restrict__ Ax) {
    int i = blockIdx.x * 256 + threadIdx.x;
    if (i >= MPAD * DIN) return;
    int n = i >> 7, k = i & 127;
    float v = (n < N_NODES) ? x[n * DIN + k] : 0.f;
    ushort_t h = f2bf(v);
    ushort_t l = f2bf(v - bf2f(h));
    int rb = n >> 7, r = n & 127;
    Ax[swz_idx(rb, r, k, 6)] = h;
    Ax[swz_idx(rb, r, 128 + k, 6)] = l;
    Ax[swz_idx(rb, r, 256 + k, 6)] = h;
}

// Bx: rows = output cols n (512), K'=384 = [hi | hi | lo];  W is [128][512]
__global__ void k_prepWft(const float* __restrict__ W, ushort_t* __restrict__ Bx) {
    int i = blockIdx.x * 256 + threadIdx.x;
    if (i >= DIN * DW) return;
    int n = i >> 7, k = i & 127;          // k fastest for coalesced writes
    float v = W[k * DW + n];
    ushort_t h = f2bf(v);
    ushort_t l = f2bf(v - bf2f(h));
    int cb = n >> 7, rc = n & 127;
    Bx[swz_idx(cb, rc, k, 6)] = h;
    Bx[swz_idx(cb, rc, 128 + k, 6)] = h;
    Bx[swz_idx(cb, rc, 256 + k, 6)] = l;
}

// B1: rows = output cols n (512), K'=1536 = [hi | hi | lo];  W1 is [512][512]
__global__ void k_prepW1(const float* __restrict__ W, ushort_t* __restrict__ B1) {
    int i = blockIdx.x * 256 + threadIdx.x;
    if (i >= DW * DW) return;
    int n = i >> 9, k = i & 511;          // k fastest
    float v = W[k * DW + n];
    ushort_t h = f2bf(v);
    ushort_t l = f2bf(v - bf2f(h));
    int cb = n >> 7, rc = n & 127;
    B1[swz_idx(cb, rc, k, 24)] = h;
    B1[swz_idx(cb, rc, 512 + k, 24)] = h;
    B1[swz_idx(cb, rc, 1024 + k, 24)] = l;
}

// ================= LDS-DMA double-buffered bf16 MFMA GEMM =================
// C = A[MPAD][KP] @ B[512][KP]^T ; A,B in pre-swizzled tile-major layout.
// 128x128 tile, 4 waves (64x64 each), global_load_lds + counted vmcnt(8).
template<int KP, bool ATT>
__global__ __launch_bounds__(256) void k_tgemm(const ushort_t* __restrict__ A,
                                               const ushort_t* __restrict__ Bm,
                                               float* __restrict__ C,
                                               ushort_t* __restrict__ Cb,
                                               const float* __restrict__ asrc,
                                               const float* __restrict__ adst,
                                               float* __restrict__ aS,
                                               float* __restrict__ aD) {
    constexpr int KT = KP / 64;
    __shared__ __align__(16) ushort_t As[2][8192];
    __shared__ __align__(16) ushort_t Bs[2][8192];
    int t = threadIdx.x, w = t >> 6, l = t & 63;
    int lm = l & 15, g = l >> 4;
    int wr = w >> 1, wc = w & 1;
    int rowbase = blockIdx.x * 128;
    int colbase = blockIdx.y * 128;

    const ushort_t* Abase = A + (size_t)blockIdx.x * KT * 8192 + w * 2048 + l * 8;
    const ushort_t* Bbase = Bm + (size_t)blockIdx.y * KT * 8192 + w * 2048 + l * 8;

    f32x4 acc[4][4];
    #pragma unroll
    for (int r = 0; r < 4; r++)
        #pragma unroll
        for (int c = 0; c < 4; c++) acc[r][c] = (f32x4){0.f, 0.f, 0.f, 0.f};

    // prologue: stage tile 0 into buffer 0
    {
        ushort_t* la = &As[0][w * 2048];
        ushort_t* lb = &Bs[0][w * 2048];
        #pragma unroll
        for (int j = 0; j < 4; ++j) {
            gld16(Abase + j * 512, la + j * 512);
            gld16(Bbase + j * 512, lb + j * 512);
        }
    }

    int p = 0;
    for (int kt = 0; kt < KT; ++kt) {
        __builtin_amdgcn_s_barrier();     // all waves done reading buf[p^1] (prev iter)
        if (kt + 1 < KT) {
            const ushort_t* ga = Abase + (size_t)(kt + 1) * 8192;
            const ushort_t* gb = Bbase + (size_t)(kt + 1) * 8192;
            ushort_t* la = &As[p ^ 1][w * 2048];
            ushort_t* lb = &Bs[p ^ 1][w * 2048];
            #pragma unroll
            for (int j = 0; j < 4; ++j) {
                gld16(ga + j * 512, la + j * 512);
                gld16(gb + j * 512, lb + j * 512);
            }
            asm volatile("s_waitcnt vmcnt(8)" ::: "memory");   // own tile-kt loads done
        } else {
            asm volatile("s_waitcnt vmcnt(0)" ::: "memory");
        }
        __builtin_amdgcn_s_barrier();     // => ALL waves' tile-kt DMA complete
        const char* Ap = (const char*)As[p];
        const char* Bp = (const char*)Bs[p];
        #pragma unroll
        for (int ks = 0; ks < 2; ++ks) {
            bf16x8 af[4], bfr[4];
            #pragma unroll
            for (int r = 0; r < 4; ++r) {
                int row = wr * 64 + r * 16 + lm;
                af[r] = *(const bf16x8*)(Ap + row * 128 +
                                         ((ks * 64 + g * 16) ^ ((row & 7) << 4)));
            }
            #pragma unroll
            for (int c = 0; c < 4; ++c) {
                int col = wc * 64 + c * 16 + lm;
                bfr[c] = *(const bf16x8*)(Bp + col * 128 +
                                          ((ks * 64 + g * 16) ^ ((col & 7) << 4)));
            }
            #pragma unroll
            for (int r = 0; r < 4; ++r)
                #pragma unroll
                for (int c = 0; c < 4; ++c)
                    acc[r][c] = __builtin_amdgcn_mfma_f32_16x16x32_bf16(af[r], bfr[c], acc[r][c], 0, 0, 0);
        }
        p ^= 1;
    }

    // C/D map: col = lane&15, row = (lane>>4)*4 + q
    if (!ATT) {
        #pragma unroll
        for (int r = 0; r < 4; ++r) {
            int row0 = rowbase + wr * 64 + r * 16 + g * 4;
            #pragma unroll
            for (int c = 0; c < 4; ++c) {
                int col = colbase + wc * 64 + c * 16 + lm;
                #pragma unroll
                for (int q = 0; q < 4; ++q)
                    if (row0 + q < N_NODES) C[(size_t)(row0 + q) * DW + col] = acc[r][c][q];
            }
        }
    } else {
        int h = 2 * blockIdx.y + wc;                  // this wave's head
        float asv[4], adv[4];
        #pragma unroll
        for (int c = 0; c < 4; ++c) {
            asv[c] = asrc[h * NC + c * 16 + lm];
            adv[c] = adst[h * NC + c * 16 + lm];
        }
        #pragma unroll
        for (int r = 0; r < 4; ++r) {
            int row0 = rowbase + wr * 64 + r * 16 + g * 4;
            #pragma unroll
            for (int c = 0; c < 4; ++c) {
                int col = colbase + wc * 64 + c * 16 + lm;
                #pragma unroll
                for (int q = 0; q < 4; ++q)
                    if (row0 + q < N_NODES) Cb[(size_t)(row0 + q) * DW + col] = f2bf(acc[r][c][q]);
            }
            #pragma unroll
            for (int q = 0; q < 4; ++q) {
                float ss = acc[r][0][q] * asv[0] + acc[r][1][q] * asv[1] +
                           acc[r][2][q] * asv[2] + acc[r][3][q] * asv[3];
                float dd = acc[r][0][q] * adv[0] + acc[r][1][q] * adv[1] +
                           acc[r][2][q] * adv[2] + acc[r][3][q] * adv[3];
                #pragma unroll
                for (int m = 1; m < 16; m <<= 1) {
                    ss += __shfl_xor(ss, m, 64);
                    dd += __shfl_xor(dd, m, 64);
                }
                int row = row0 + q;
                if (lm == 0 && row < N_NODES) {
                    aS[row * NHEAD + h] = ss;
                    aD[row * NHEAD + h] = dd;
                }
            }
        }
    }
}

// ================= LN epilogue -> h0big tiles K'=1536 = [hi | lo | hi] =================
__global__ __launch_bounds__(256) void k_ln(const float* __restrict__ hpre,
                                            const float* __restrict__ fb,
                                            const float* __restrict__ g,
                                            const float* __restrict__ beta,
                                            ushort_t* __restrict__ h0big) {
    int n = blockIdx.x, t = threadIdx.x;
    int rb = n >> 7, r = n & 127;
    if (n >= N_NODES) {
        #pragma unroll
        for (int j = 0; j < 6; j++)
            h0big[swz_idx(rb, r, t + j * 256, 24)] = 0;
        return;
    }
    __shared__ float red[8];
    float a0 = hpre[(size_t)n * DW + t] + fb[t];
    float a1 = hpre[(size_t)n * DW + t + 256] + fb[t + 256];
    float s = a0 + a1, sq = a0 * a0 + a1 * a1;
    for (int o = 32; o > 0; o >>= 1) { s += __shfl_down(s, o, 64); sq += __shfl_down(sq, o, 64); }
    int wid = t >> 6;
    if ((t & 63) == 0) { red[wid] = s; red[4 + wid] = sq; }
    __syncthreads();
    if (t == 0) {
        float ts = red[0] + red[1] + red[2] + red[3];
        float tq = red[4] + red[5] + red[6] + red[7];
        float mu = ts / DW;
        float var = tq / DW - mu * mu;
        red[0] = mu; red[1] = rsqrtf(var + 1e-5f);
    }
    __syncthreads();
    float mu = red[0], rs = red[1];
    float v0 = (a0 - mu) * rs * g[t] + beta[t];
    float v1 = (a1 - mu) * rs * g[t + 256] + beta[t + 256];
    v0 = v0 >= 0.f ? v0 : 0.2f * v0;
    v1 = v1 >= 0.f ? v1 : 0.2f * v1;
    ushort_t h0_ = f2bf(v0), l0_ = f2bf(v0 - bf2f(h0_));
    ushort_t h1_ = f2bf(v1), l1_ = f2bf(v1 - bf2f(h1_));
    h0big[swz_idx(rb, r, t, 24)] = h0_;
    h0big[swz_idx(rb, r, 512 + t, 24)] = l0_;
    h0big[swz_idx(rb, r, 1024 + t, 24)] = h0_;
    h0big[swz_idx(rb, r, 256 + t, 24)] = h1_;
    h0big[swz_idx(rb, r, 768 + t, 24)] = l1_;
    h0big[swz_idx(rb, r, 1280 + t, 24)] = h1_;
}

// ================= layer-1 aggregation: bf16 gather, fused softmax+bias+BN+ReLU -> bf16 h2 =================
__global__ __launch_bounds__(256) void k_agg1csr(
    const int* __restrict__ csrc, const int* __restrict__ off,
    const ushort_t* __restrict__ h1b,
    const float* __restrict__ aS, const float* __restrict__ aD,
    const float* __restrict__ b1, const float* __restrict__ bnm,
    const float* __restrict__ bnv, const float* __restrict__ bng,
    const float* __restrict__ bnb, ushort_t* __restrict__ h2b)
{
    int n = blockIdx.x, t = threadIdx.x;
    int beg = off[n], end = off[n + 1];
    __shared__ float wls[64][NHEAD];
    __shared__ int   sls[64];
    __shared__ float aDn[NHEAD];
    __shared__ float dsum[NHEAD];
    if (t < NHEAD) { aDn[t] = aD[n * NHEAD + t]; dsum[t] = 0.f; }
    __syncthreads();
    float acc0 = 0.f, acc1 = 0.f, dpart = 0.f;
    int hA = t >> 5;                       // head of cols 2t, 2t+1
    for (int c = beg; c < end; c += 64) {
        int m = min(64, end - c);
        if (t < m) sls[t] = csrc[c + t];
        __syncthreads();
        for (int idx = t; idx < m * NHEAD; idx += 256) {
            int el = idx >> 3, h = idx & 7;
            float l = aS[sls[el] * NHEAD + h] + aDn[h];
            l = l >= 0.f ? l : 0.2f * l;
            float w = __expf(l);
            wls[el][h] = w;
            dpart += w;
        }
        __syncthreads();
        for (int el = 0; el < m; el++) {
            float w = wls[el][hA];
            unsigned v = *(const unsigned*)(h1b + (size_t)sls[el] * DW + 2 * t);
            acc0 += w * __builtin_bit_cast(float, v << 16);
            acc1 += w * __builtin_bit_cast(float, v & 0xffff0000u);
        }
        __syncthreads();
    }
    for (int o = 8; o < 64; o <<= 1) dpart += __shfl_down(dpart, o, 64);
    if ((t & 63) < NHEAD) atomicAdd(&dsum[t & 7], dpart);
    __syncthreads();
    float rd = dsum[hA] > 0.f ? 1.f / dsum[hA] : 0.f;
    int j0 = 2 * t, j1 = 2 * t + 1;
    float v0 = acc0 * rd + b1[j0];
    v0 = (v0 - bnm[j0]) * rsqrtf(bnv[j0] + 1e-5f) * bng[j0] + bnb[j0];
    v0 = v0 > 0.f ? v0 : 0.f;
    float v1 = acc1 * rd + b1[j1];
    v1 = (v1 - bnm[j1]) * rsqrtf(bnv[j1] + 1e-5f) * bng[j1] + bnb[j1];
    v1 = v1 > 0.f ? v1 : 0.f;
    unsigned pk = (unsigned)f2bf(v0) | ((unsigned)f2bf(v1) << 16);
    *(unsigned*)(h2b + (size_t)n * DW + 2 * t) = pk;
}

// ================= GEMM2: g = h2(bf16) @ W2 [512,16] =================
__global__ __launch_bounds__(256) void k_gemm2(const ushort_t* __restrict__ h2b,
                                               const float* __restrict__ W2,
                                               float* __restrict__ gout) {
    __shared__ float Ws[DW * 16];
    int t = threadIdx.x;
    for (int i = t; i < DW * 16; i += 256) Ws[i] = W2[i];
    __syncthreads();
    int nb = blockIdx.x * 16;
    int nl = t >> 4, j = t & 15;
    const ushort_t* hr = h2b + (size_t)(nb + nl) * DW;
    float acc = 0.f;
    for (int k = 0; k < DW; k++) acc += bf2f(hr[k]) * Ws[k * 16 + j];
    gout[(nb + nl) * 16 + j] = acc;
}

// ================= attention dots layer 2 =================
__global__ void k_att2(const float* __restrict__ gout, const float* __restrict__ as2,
                       const float* __restrict__ ad2, float* __restrict__ a_s,
                       float* __restrict__ a_d) {
    int idx = blockIdx.x * 256 + threadIdx.x;
    if (idx >= N_NODES * NHEAD) return;
    int n = idx >> 3, h = idx & 7;
    float g0 = gout[n * 16 + 2 * h], g1 = gout[n * 16 + 2 * h + 1];
    a_s[idx] = g0 * as2[2 * h] + g1 * as2[2 * h + 1];
    a_d[idx] = g0 * ad2[2 * h] + g1 * ad2[2 * h + 1];
}

// ================= layer-2 aggregation, CSR, fused head-mean + b2 =================
__global__ __launch_bounds__(256) void k_agg2csr(
    const int* __restrict__ csrc, const int* __restrict__ off,
    const float* __restrict__ gbuf,
    const float* __restrict__ aS, const float* __restrict__ aD,
    const float* __restrict__ b2, float* __restrict__ outp)
{
    int t = threadIdx.x;
    int n = blockIdx.x * 4 + (t >> 6);
    int lane = t & 63;
    if (n >= N_NODES) return;
    int beg = off[n], end = off[n + 1];
    int j = lane & 15, slot = lane >> 4, h = j >> 1;
    float adn = aD[n * NHEAD + h];
    float acc = 0.f, den = 0.f;
    for (int c = beg + slot; c < end; c += 4) {
        int s = csrc[c];
        float l = aS[s * NHEAD + h] + adn;
        l = l >= 0.f ? l : 0.2f * l;
        float w = __expf(l);
        den += w;
        acc += w * gbuf[s * 16 + j];
    }
    acc += __shfl_down(acc, 16, 64); acc += __shfl_down(acc, 32, 64);
    den += __shfl_down(den, 16, 64); den += __shfl_down(den, 32, 64);
    float v = (lane < 16 && den > 0.f) ? acc / den : 0.f;
    v += __shfl_down(v, 2, 64);
    v += __shfl_down(v, 4, 64);
    v += __shfl_down(v, 8, 64);
    if (lane < 2) outp[n * 2 + lane] = v * 0.125f + b2[lane];
}

extern "C" void kernel_launch(void* const* d_in, const int* in_sizes, int n_in,
                              void* d_out, int out_size, void* d_ws, size_t ws_size,
                              hipStream_t stream) {
    const float* x    = (const float*)d_in[0];
    const int*   ei   = (const int*)d_in[1];
    const float* ftW  = (const float*)d_in[2];
    const float* ftb  = (const float*)d_in[3];
    const float* lng  = (const float*)d_in[4];
    const float* lnb  = (const float*)d_in[5];
    const float* W1   = (const float*)d_in[6];
    const float* as1  = (const float*)d_in[7];
    const float* ad1  = (const float*)d_in[8];
    const float* b1   = (const float*)d_in[9];
    const float* bng  = (const float*)d_in[10];
    const float* bnb  = (const float*)d_in[11];
    const float* bnm  = (const float*)d_in[12];
    const float* bnv  = (const float*)d_in[13];
    const float* W2   = (const float*)d_in[14];
    const float* as2  = (const float*)d_in[15];
    const float* ad2  = (const float*)d_in[16];
    const float* b2   = (const float*)d_in[17];
    float* out = (float*)d_out;

    // ---- workspace (float offsets), lifetime-aliased, ~63.3 MB ----
    float* F = (float*)d_ws;
    // R0 [0, 2,588,672): {Ax, Bx, cnt, cursor} -> h1b -> gbuf
    ushort_t* Ax   = (ushort_t*)(F + 0);           // 79*6*8192 us = 1,941,504 f
    ushort_t* Bx   = (ushort_t*)(F + 1941504);     // 4*6*8192 us  = 98,304 f
    int* cnt       = (int*)(F + 2039808);
    int* cursor    = (int*)(F + 2049808);
    ushort_t* h1b  = (ushort_t*)(F + 0);           // 10000*512 us
    float* gbuf    = F + 0;                        // 160,000 f (after h1b dead)
    // R1 [2,588,672, 7,708,672): hpre -> B1 -> h2b
    float* hpre    = F + 2588672;                  // 10000*512 f
    ushort_t* B1   = (ushort_t*)(F + 2588672);     // 4*24*8192 us = 393,216 f
    ushort_t* h2b  = (ushort_t*)(F + 2588672);     // 10000*512 us
    float* aS1     = F + 7708672;                  // 80,000 (reused layer 2)
    float* aD1     = F + 7788672;                  // 80,000
    ushort_t* h0big = (ushort_t*)(F + 7868672);    // 79*24*8192 us = 7,766,016 f
    int* off       = (int*)(F + 15634688);         // 10,001
    int* csrc      = (int*)(F + 15644689);         // 160,000 -> end 15,804,689 f

    // CSR build
    k_zero<<<40, 256, 0, stream>>>(cnt, cursor);
    k_count<<<(N_EDGES + 255) / 256, 256, 0, stream>>>(ei, cnt);
    k_scan<<<1, 256, 0, stream>>>(cnt, off);
    k_scatter<<<(N_EDGES + 255) / 256, 256, 0, stream>>>(ei, off, cursor, csrc);

    // operand prep + ft GEMM + LN
    k_prepx<<<(MPAD * DIN + 255) / 256, 256, 0, stream>>>(x, Ax);
    k_prepWft<<<(DIN * DW + 255) / 256, 256, 0, stream>>>(ftW, Bx);
    dim3 gg(MPAD / 128, DW / 128);
    k_tgemm<384, false><<<gg, 256, 0, stream>>>(Ax, Bx, hpre, nullptr, nullptr, nullptr, nullptr, nullptr);
    k_ln<<<MPAD, 256, 0, stream>>>(hpre, ftb, lng, lnb, h0big);
    k_prepW1<<<(DW * DW + 255) / 256, 256, 0, stream>>>(W1, B1);
    // GEMM1 with fused attention dots + bf16 output
    k_tgemm<1536, true><<<gg, 256, 0, stream>>>(h0big, B1, nullptr, h1b, as1, ad1, aS1, aD1);

    k_agg1csr<<<N_NODES, 256, 0, stream>>>(csrc, off, h1b, aS1, aD1, b1, bnm, bnv, bng, bnb, h2b);
    k_gemm2<<<N_NODES / 16, 256, 0, stream>>>(h2b, W2, gbuf);      // h1b dead now
    k_att2<<<(N_NODES * NHEAD + 255) / 256, 256, 0, stream>>>(gbuf, as2, ad2, aS1, aD1);
    k_agg2csr<<<(N_NODES + 3) / 4, 256, 0, stream>>>(csrc, off, gbuf, aS1, aD1, b2, out);
}

// Round 7
// 131.009 us; speedup vs baseline: 4.0469x; 1.3003x over previous
//
#include <hip/hip_runtime.h>
#include <hip/hip_bf16.h>
#include <math.h>

#define N_NODES 10000
#define N_EDGES 160000
#define DIN 128
#define DW 512
#define NHEAD 8
#define NC 64
#define MPAD 10112   // 79 * 128
#define GEMM_BLKS 316  // 79 * 4

typedef unsigned short ushort_t;
typedef __attribute__((ext_vector_type(8))) short bf16x8;
typedef __attribute__((ext_vector_type(4))) float f32x4;

__device__ inline ushort_t f2bf(float v) {
    unsigned u = __builtin_bit_cast(unsigned, v);
    return (ushort_t)((u + 0x7fff + ((u >> 16) & 1)) >> 16);
}
__device__ inline float bf2f(ushort_t h) {
    return __builtin_bit_cast(float, (unsigned)h << 16);
}

// swizzled tile-major index: tiles of 128 rows x 64 k, 8192 ushort each.
// within tile: us = r*64 + (kc ^ ((r&7)<<3))  == byte ^ ((r&7)<<4)
__device__ __forceinline__ size_t swz_idx(int rb, int r, int kp, int nkt) {
    int kt = kp >> 6, kc = kp & 63;
    return ((size_t)(rb * nkt + kt)) * 8192 + r * 64 + (kc ^ ((r & 7) << 3));
}

__device__ __forceinline__ void gld16(const ushort_t* g, ushort_t* l) {
    __builtin_amdgcn_global_load_lds(
        (const __attribute__((address_space(1))) void*)g,
        (__attribute__((address_space(3))) void*)l, 16, 0, 0);
}

// ================= merged prep: zero + prepx + prepWft + prepW1 =================
// 2-term split: A-side = [hi | lo], B-side = [hi | hi]
__global__ void k_prep(const float* __restrict__ x, const float* __restrict__ ftW,
                       const float* __restrict__ W1f,
                       ushort_t* __restrict__ Ax, ushort_t* __restrict__ Bx,
                       ushort_t* __restrict__ B1,
                       int* __restrict__ cnt, int* __restrict__ cursor) {
    int bid = blockIdx.x, t = threadIdx.x;
    if (bid < 5056) {                       // prepx: Ax[MPAD][256] = [xhi | xlo]
        int i = bid * 256 + t;
        int n = i >> 7, k = i & 127;
        float v = (n < N_NODES) ? x[n * DIN + k] : 0.f;
        ushort_t h = f2bf(v);
        ushort_t l = f2bf(v - bf2f(h));
        int rb = n >> 7, r = n & 127;
        Ax[swz_idx(rb, r, k, 4)] = h;
        Ax[swz_idx(rb, r, 128 + k, 4)] = l;
    } else if (bid < 5312) {                // prepWft: Bx[512][256] = [Whi | Whi]
        int i = (bid - 5056) * 256 + t;
        int n = i >> 7, k = i & 127;
        ushort_t h = f2bf(ftW[k * DW + n]);
        int cb = n >> 7, rc = n & 127;
        Bx[swz_idx(cb, rc, k, 4)] = h;
        Bx[swz_idx(cb, rc, 128 + k, 4)] = h;
    } else if (bid < 6336) {                // prepW1: B1[512][1024] = [W1hi | W1hi]
        int i = (bid - 5312) * 256 + t;
        int n = i >> 9, k = i & 511;
        ushort_t h = f2bf(W1f[k * DW + n]);
        int cb = n >> 7, rc = n & 127;
        B1[swz_idx(cb, rc, k, 16)] = h;
        B1[swz_idx(cb, rc, 512 + k, 16)] = h;
    } else {                                // zero cnt/cursor
        int i = (bid - 6336) * 256 + t;
        if (i < N_NODES) { cnt[i] = 0; cursor[i] = 0; }
    }
}

// ================= LDS-DMA double-buffered bf16 MFMA GEMM (+side work) =================
// C = A[MPAD][KT*64] @ B[512][KT*64]^T ; pre-swizzled tile-major operands.
// EXTRA: 1 = CSR count, 2 = CSR scatter (blocks >= GEMM_BLKS).
template<int KT, bool ATT, int EXTRA>
__global__ __launch_bounds__(256) void k_tgemm(const ushort_t* __restrict__ A,
                                               const ushort_t* __restrict__ Bm,
                                               float* __restrict__ C,
                                               ushort_t* __restrict__ Cb,
                                               const float* __restrict__ asrc,
                                               const float* __restrict__ adst,
                                               float* __restrict__ aS,
                                               float* __restrict__ aD,
                                               const int* __restrict__ ei,
                                               int* __restrict__ cnt,
                                               const int* __restrict__ off,
                                               int* __restrict__ cursor,
                                               int* __restrict__ csrc) {
    __shared__ __align__(16) ushort_t As[2][8192];
    __shared__ __align__(16) ushort_t Bs[2][8192];
    int bid = blockIdx.x;
    if (bid >= GEMM_BLKS) {                 // ---- CSR side work ----
        int e = (bid - GEMM_BLKS) * 256 + threadIdx.x;
        if (e < N_EDGES) {
            if (EXTRA == 1) {
                atomicAdd(&cnt[ei[N_EDGES + e]], 1);
            } else {
                int d = ei[N_EDGES + e];
                int p = off[d] + atomicAdd(&cursor[d], 1);
                csrc[p] = ei[e];
            }
        }
        return;
    }
    int bx = bid >> 2, by = bid & 3;
    int t = threadIdx.x, w = t >> 6, l = t & 63;
    int lm = l & 15, g = l >> 4;
    int wr = w >> 1, wc = w & 1;
    int rowbase = bx * 128;
    int colbase = by * 128;

    const ushort_t* Abase = A + (size_t)bx * KT * 8192 + w * 2048 + l * 8;
    const ushort_t* Bbase = Bm + (size_t)by * KT * 8192 + w * 2048 + l * 8;

    f32x4 acc[4][4];
    #pragma unroll
    for (int r = 0; r < 4; r++)
        #pragma unroll
        for (int c = 0; c < 4; c++) acc[r][c] = (f32x4){0.f, 0.f, 0.f, 0.f};

    {   // prologue: tile 0 -> buf 0
        ushort_t* la = &As[0][w * 2048];
        ushort_t* lb = &Bs[0][w * 2048];
        #pragma unroll
        for (int j = 0; j < 4; ++j) {
            gld16(Abase + j * 512, la + j * 512);
            gld16(Bbase + j * 512, lb + j * 512);
        }
    }

    int p = 0;
    for (int kt = 0; kt < KT; ++kt) {
        __builtin_amdgcn_s_barrier();
        if (kt + 1 < KT) {
            const ushort_t* ga = Abase + (size_t)(kt + 1) * 8192;
            const ushort_t* gb = Bbase + (size_t)(kt + 1) * 8192;
            ushort_t* la = &As[p ^ 1][w * 2048];
            ushort_t* lb = &Bs[p ^ 1][w * 2048];
            #pragma unroll
            for (int j = 0; j < 4; ++j) {
                gld16(ga + j * 512, la + j * 512);
                gld16(gb + j * 512, lb + j * 512);
            }
            asm volatile("s_waitcnt vmcnt(8)" ::: "memory");
        } else {
            asm volatile("s_waitcnt vmcnt(0)" ::: "memory");
        }
        __builtin_amdgcn_s_barrier();
        const char* Ap = (const char*)As[p];
        const char* Bp = (const char*)Bs[p];
        #pragma unroll
        for (int ks = 0; ks < 2; ++ks) {
            bf16x8 af[4], bfr[4];
            #pragma unroll
            for (int r = 0; r < 4; ++r) {
                int row = wr * 64 + r * 16 + lm;
                af[r] = *(const bf16x8*)(Ap + row * 128 +
                                         ((ks * 64 + g * 16) ^ ((row & 7) << 4)));
            }
            #pragma unroll
            for (int c = 0; c < 4; ++c) {
                int col = wc * 64 + c * 16 + lm;
                bfr[c] = *(const bf16x8*)(Bp + col * 128 +
                                          ((ks * 64 + g * 16) ^ ((col & 7) << 4)));
            }
            #pragma unroll
            for (int r = 0; r < 4; ++r)
                #pragma unroll
                for (int c = 0; c < 4; ++c)
                    acc[r][c] = __builtin_amdgcn_mfma_f32_16x16x32_bf16(af[r], bfr[c], acc[r][c], 0, 0, 0);
        }
        p ^= 1;
    }

    // C/D map: col = lane&15, row = (lane>>4)*4 + q
    if (!ATT) {
        #pragma unroll
        for (int r = 0; r < 4; ++r) {
            int row0 = rowbase + wr * 64 + r * 16 + g * 4;
            #pragma unroll
            for (int c = 0; c < 4; ++c) {
                int col = colbase + wc * 64 + c * 16 + lm;
                #pragma unroll
                for (int q = 0; q < 4; ++q)
                    if (row0 + q < N_NODES) C[(size_t)(row0 + q) * DW + col] = acc[r][c][q];
            }
        }
    } else {
        int h = 2 * by + wc;                  // this wave's head
        float asv[4], adv[4];
        #pragma unroll
        for (int c = 0; c < 4; ++c) {
            asv[c] = asrc[h * NC + c * 16 + lm];
            adv[c] = adst[h * NC + c * 16 + lm];
        }
        #pragma unroll
        for (int r = 0; r < 4; ++r) {
            int row0 = rowbase + wr * 64 + r * 16 + g * 4;
            #pragma unroll
            for (int c = 0; c < 4; ++c) {
                int col = colbase + wc * 64 + c * 16 + lm;
                #pragma unroll
                for (int q = 0; q < 4; ++q)
                    if (row0 + q < N_NODES) Cb[(size_t)(row0 + q) * DW + col] = f2bf(acc[r][c][q]);
            }
            #pragma unroll
            for (int q = 0; q < 4; ++q) {
                float ss = acc[r][0][q] * asv[0] + acc[r][1][q] * asv[1] +
                           acc[r][2][q] * asv[2] + acc[r][3][q] * asv[3];
                float dd = acc[r][0][q] * adv[0] + acc[r][1][q] * adv[1] +
                           acc[r][2][q] * adv[2] + acc[r][3][q] * adv[3];
                #pragma unroll
                for (int m = 1; m < 16; m <<= 1) {
                    ss += __shfl_xor(ss, m, 64);
                    dd += __shfl_xor(dd, m, 64);
                }
                int row = row0 + q;
                if (lm == 0 && row < N_NODES) {
                    aS[row * NHEAD + h] = ss;
                    aD[row * NHEAD + h] = dd;
                }
            }
        }
    }
}

// ================= LN epilogue -> h0big[*][1024] = [hi | lo]  (+ CSR scan block) =================
__global__ __launch_bounds__(256) void k_ln_scan(const float* __restrict__ hpre,
                                                 const float* __restrict__ fb,
                                                 const float* __restrict__ g,
                                                 const float* __restrict__ beta,
                                                 ushort_t* __restrict__ h0big,
                                                 const int* __restrict__ cnt,
                                                 int* __restrict__ off) {
    __shared__ int ps[256];
    __shared__ float red[8];
    int bid = blockIdx.x, t = threadIdx.x;
    if (bid == MPAD) {                       // ---- exclusive scan over cnt ----
        int base = t * 40;
        int loc[40];
        int s = 0;
        #pragma unroll
        for (int i = 0; i < 40; i++) {
            int idx = base + i;
            int v = idx < N_NODES ? cnt[idx] : 0;
            loc[i] = s; s += v;
        }
        ps[t] = s; __syncthreads();
        for (int o = 1; o < 256; o <<= 1) {
            int v = (t >= o) ? ps[t - o] : 0;
            __syncthreads();
            ps[t] += v;
            __syncthreads();
        }
        int pre = (t > 0) ? ps[t - 1] : 0;
        #pragma unroll
        for (int i = 0; i < 40; i++) {
            int idx = base + i;
            if (idx < N_NODES) off[idx] = pre + loc[i];
        }
        if (t == 255) off[N_NODES] = ps[255];
        return;
    }
    int n = bid;
    int rb = n >> 7, r = n & 127;
    if (n >= N_NODES) {
        #pragma unroll
        for (int j = 0; j < 4; j++)
            h0big[swz_idx(rb, r, t + j * 256, 16)] = 0;
        return;
    }
    float a0 = hpre[(size_t)n * DW + t] + fb[t];
    float a1 = hpre[(size_t)n * DW + t + 256] + fb[t + 256];
    float s = a0 + a1, sq = a0 * a0 + a1 * a1;
    for (int o = 32; o > 0; o >>= 1) { s += __shfl_down(s, o, 64); sq += __shfl_down(sq, o, 64); }
    int wid = t >> 6;
    if ((t & 63) == 0) { red[wid] = s; red[4 + wid] = sq; }
    __syncthreads();
    if (t == 0) {
        float ts = red[0] + red[1] + red[2] + red[3];
        float tq = red[4] + red[5] + red[6] + red[7];
        float mu = ts / DW;
        float var = tq / DW - mu * mu;
        red[0] = mu; red[1] = rsqrtf(var + 1e-5f);
    }
    __syncthreads();
    float mu = red[0], rs = red[1];
    float v0 = (a0 - mu) * rs * g[t] + beta[t];
    float v1 = (a1 - mu) * rs * g[t + 256] + beta[t + 256];
    v0 = v0 >= 0.f ? v0 : 0.2f * v0;
    v1 = v1 >= 0.f ? v1 : 0.2f * v1;
    ushort_t h0_ = f2bf(v0), l0_ = f2bf(v0 - bf2f(h0_));
    ushort_t h1_ = f2bf(v1), l1_ = f2bf(v1 - bf2f(h1_));
    h0big[swz_idx(rb, r, t, 16)] = h0_;
    h0big[swz_idx(rb, r, 512 + t, 16)] = l0_;
    h0big[swz_idx(rb, r, 256 + t, 16)] = h1_;
    h0big[swz_idx(rb, r, 768 + t, 16)] = l1_;
}

// ================= layer-1 aggregation: bf16 gather, fused softmax+bias+BN+ReLU -> bf16 h2 =================
__global__ __launch_bounds__(256) void k_agg1csr(
    const int* __restrict__ csrc, const int* __restrict__ off,
    const ushort_t* __restrict__ h1b,
    const float* __restrict__ aS, const float* __restrict__ aD,
    const float* __restrict__ b1, const float* __restrict__ bnm,
    const float* __restrict__ bnv, const float* __restrict__ bng,
    const float* __restrict__ bnb, ushort_t* __restrict__ h2b)
{
    int n = blockIdx.x, t = threadIdx.x;
    int beg = off[n], end = off[n + 1];
    __shared__ float wls[64][NHEAD];
    __shared__ int   sls[64];
    __shared__ float aDn[NHEAD];
    __shared__ float dsum[NHEAD];
    if (t < NHEAD) { aDn[t] = aD[n * NHEAD + t]; dsum[t] = 0.f; }
    __syncthreads();
    float acc0 = 0.f, acc1 = 0.f, dpart = 0.f;
    int hA = t >> 5;                       // head of cols 2t, 2t+1
    for (int c = beg; c < end; c += 64) {
        int m = min(64, end - c);
        if (t < m) sls[t] = csrc[c + t];
        __syncthreads();
        for (int idx = t; idx < m * NHEAD; idx += 256) {
            int el = idx >> 3, h = idx & 7;
            float l = aS[sls[el] * NHEAD + h] + aDn[h];
            l = l >= 0.f ? l : 0.2f * l;
            float w = __expf(l);
            wls[el][h] = w;
            dpart += w;
        }
        __syncthreads();
        for (int el = 0; el < m; el++) {
            float w = wls[el][hA];
            unsigned v = *(const unsigned*)(h1b + (size_t)sls[el] * DW + 2 * t);
            acc0 += w * __builtin_bit_cast(float, v << 16);
            acc1 += w * __builtin_bit_cast(float, v & 0xffff0000u);
        }
        __syncthreads();
    }
    for (int o = 8; o < 64; o <<= 1) dpart += __shfl_down(dpart, o, 64);
    if ((t & 63) < NHEAD) atomicAdd(&dsum[t & 7], dpart);
    __syncthreads();
    float rd = dsum[hA] > 0.f ? 1.f / dsum[hA] : 0.f;
    int j0 = 2 * t, j1 = 2 * t + 1;
    float v0 = acc0 * rd + b1[j0];
    v0 = (v0 - bnm[j0]) * rsqrtf(bnv[j0] + 1e-5f) * bng[j0] + bnb[j0];
    v0 = v0 > 0.f ? v0 : 0.f;
    float v1 = acc1 * rd + b1[j1];
    v1 = (v1 - bnm[j1]) * rsqrtf(bnv[j1] + 1e-5f) * bng[j1] + bnb[j1];
    v1 = v1 > 0.f ? v1 : 0.f;
    unsigned pk = (unsigned)f2bf(v0) | ((unsigned)f2bf(v1) << 16);
    *(unsigned*)(h2b + (size_t)n * DW + 2 * t) = pk;
}

// ================= GEMM2 + fused att2: g = h2(bf16) @ W2, aS2/aD2 from g =================
__global__ __launch_bounds__(256) void k_gemm2att(const ushort_t* __restrict__ h2b,
                                                  const float* __restrict__ W2,
                                                  const float* __restrict__ as2,
                                                  const float* __restrict__ ad2,
                                                  float* __restrict__ gout,
                                                  float* __restrict__ aS,
                                                  float* __restrict__ aD) {
    __shared__ float Ws[DW * 16];
    __shared__ float gl[16][16];
    __shared__ float a2[32];
    int t = threadIdx.x;
    for (int i = t; i < DW * 16; i += 256) Ws[i] = W2[i];
    if (t < 16) a2[t] = as2[t];
    else if (t < 32) a2[t] = ad2[t - 16];
    __syncthreads();
    int nb = blockIdx.x * 16;
    int nl = t >> 4, j = t & 15;
    const bf16x8* hr = (const bf16x8*)(h2b + (size_t)(nb + nl) * DW);
    float acc = 0.f;
    for (int ks = 0; ks < DW / 8; ks++) {
        bf16x8 v = hr[ks];
        #pragma unroll
        for (int u = 0; u < 8; u++)
            acc += bf2f((ushort_t)v[u]) * Ws[(ks * 8 + u) * 16 + j];
    }
    gout[(nb + nl) * 16 + j] = acc;
    gl[nl][j] = acc;
    __syncthreads();
    if (j < 8) {
        aS[(nb + nl) * NHEAD + j] = gl[nl][2 * j] * a2[2 * j] + gl[nl][2 * j + 1] * a2[2 * j + 1];
    } else {
        int h = j - 8;
        aD[(nb + nl) * NHEAD + h] = gl[nl][2 * h] * a2[16 + 2 * h] + gl[nl][2 * h + 1] * a2[16 + 2 * h + 1];
    }
}

// ================= layer-2 aggregation, CSR, fused head-mean + b2 =================
__global__ __launch_bounds__(256) void k_agg2csr(
    const int* __restrict__ csrc, const int* __restrict__ off,
    const float* __restrict__ gbuf,
    const float* __restrict__ aS, const float* __restrict__ aD,
    const float* __restrict__ b2, float* __restrict__ outp)
{
    int t = threadIdx.x;
    int n = blockIdx.x * 4 + (t >> 6);
    int lane = t & 63;
    if (n >= N_NODES) return;
    int beg = off[n], end = off[n + 1];
    int j = lane & 15, slot = lane >> 4, h = j >> 1;
    float adn = aD[n * NHEAD + h];
    float acc = 0.f, den = 0.f;
    for (int c = beg + slot; c < end; c += 4) {
        int s = csrc[c];
        float l = aS[s * NHEAD + h] + adn;
        l = l >= 0.f ? l : 0.2f * l;
        float w = __expf(l);
        den += w;
        acc += w * gbuf[s * 16 + j];
    }
    acc += __shfl_down(acc, 16, 64); acc += __shfl_down(acc, 32, 64);
    den += __shfl_down(den, 16, 64); den += __shfl_down(den, 32, 64);
    float v = (lane < 16 && den > 0.f) ? acc / den : 0.f;
    v += __shfl_down(v, 2, 64);
    v += __shfl_down(v, 4, 64);
    v += __shfl_down(v, 8, 64);
    if (lane < 2) outp[n * 2 + lane] = v * 0.125f + b2[lane];
}

extern "C" void kernel_launch(void* const* d_in, const int* in_sizes, int n_in,
                              void* d_out, int out_size, void* d_ws, size_t ws_size,
                              hipStream_t stream) {
    const float* x    = (const float*)d_in[0];
    const int*   ei   = (const int*)d_in[1];
    const float* ftW  = (const float*)d_in[2];
    const float* ftb  = (const float*)d_in[3];
    const float* lng  = (const float*)d_in[4];
    const float* lnb  = (const float*)d_in[5];
    const float* W1   = (const float*)d_in[6];
    const float* as1  = (const float*)d_in[7];
    const float* ad1  = (const float*)d_in[8];
    const float* b1   = (const float*)d_in[9];
    const float* bng  = (const float*)d_in[10];
    const float* bnb  = (const float*)d_in[11];
    const float* bnm  = (const float*)d_in[12];
    const float* bnv  = (const float*)d_in[13];
    const float* W2   = (const float*)d_in[14];
    const float* as2  = (const float*)d_in[15];
    const float* ad2  = (const float*)d_in[16];
    const float* b2   = (const float*)d_in[17];
    float* out = (float*)d_out;

    // ---- workspace (float offsets), lifetime-aliased, ~59.5 MB ----
    float* F = (float*)d_ws;
    ushort_t* Ax    = (ushort_t*)(F + 0);          // 79*4*8192 us = 1,294,336 f
    float*    gbuf  = F + 0;                       // 160,000 f (after Ax dead)
    ushort_t* Bx    = (ushort_t*)(F + 1294336);    // 4*4*8192 us = 65,536 f
    ushort_t* B1    = (ushort_t*)(F + 1359872);    // 4*16*8192 us = 262,144 f
    float*    hpre  = F + 1622016;                 // 10112*512 f = 5,177,344 f
    ushort_t* h2b   = (ushort_t*)(F + 1622016);    // 10000*512 us (after ln)
    ushort_t* h0big = (ushort_t*)(F + 6799360);    // 79*16*8192 us = 5,177,344 f
    ushort_t* h1b   = (ushort_t*)(F + 11976704);   // 10000*512 us = 2,560,000 f
    float*    aS1   = F + 14536704;                // 80,000 (reused layer 2)
    float*    aD1   = F + 14616704;                // 80,000
    int* cnt        = (int*)(F + 14696704);        // 10,000
    int* cursor     = (int*)(F + 14706704);        // 10,000
    int* off        = (int*)(F + 14716704);        // 10,001
    int* csrc       = (int*)(F + 14726705);        // 160,000 -> end 14,886,705 f

    // 1. merged prep (zero + Ax + Bx + B1)
    k_prep<<<6376, 256, 0, stream>>>(x, ftW, W1, Ax, Bx, B1, cnt, cursor);
    // 2. ft GEMM (K'=256) + CSR count
    k_tgemm<4, false, 1><<<GEMM_BLKS + 625, 256, 0, stream>>>(
        Ax, Bx, hpre, nullptr, nullptr, nullptr, nullptr, nullptr,
        ei, cnt, nullptr, nullptr, nullptr);
    // 3. LN -> h0big (K'=1024 [hi|lo]) + CSR scan
    k_ln_scan<<<MPAD + 1, 256, 0, stream>>>(hpre, ftb, lng, lnb, h0big, cnt, off);
    // 4. GEMM1 (K'=1024) + fused att-dots + CSR scatter
    k_tgemm<16, true, 2><<<GEMM_BLKS + 625, 256, 0, stream>>>(
        h0big, B1, nullptr, h1b, as1, ad1, aS1, aD1,
        ei, nullptr, off, cursor, csrc);
    // 5. layer-1 aggregation (fused softmax + bias + BN + ReLU)
    k_agg1csr<<<N_NODES, 256, 0, stream>>>(csrc, off, h1b, aS1, aD1, b1, bnm, bnv, bng, bnb, h2b);
    // 6. GEMM2 + fused att2
    k_gemm2att<<<N_NODES / 16, 256, 0, stream>>>(h2b, W2, as2, ad2, gbuf, aS1, aD1);
    // 7. layer-2 aggregation (fused head-mean + b2)
    k_agg2csr<<<(N_NODES + 3) / 4, 256, 0, stream>>>(csrc, off, gbuf, aS1, aD1, b2, out);
}

// Round 8
// 126.143 us; speedup vs baseline: 4.2030x; 1.0386x over previous
//
#include <hip/hip_runtime.h>
#include <hip/hip_bf16.h>
#include <math.h>

#define N_NODES 10000
#define N_EDGES 160000
#define DIN 128
#define DW 512
#define NHEAD 8
#define NC 64
#define MPAD 10112     // 79 * 128
#define GEMM_BLKS 316  // 79 * 4

typedef unsigned short ushort_t;
typedef __attribute__((ext_vector_type(8))) short bf16x8;
typedef __attribute__((ext_vector_type(8))) unsigned short us8;
typedef __attribute__((ext_vector_type(4))) float f32x4;

__device__ inline ushort_t f2bf(float v) {
    unsigned u = __builtin_bit_cast(unsigned, v);
    return (ushort_t)((u + 0x7fff + ((u >> 16) & 1)) >> 16);
}
__device__ inline float bf2f(ushort_t h) {
    return __builtin_bit_cast(float, (unsigned)h << 16);
}

// swizzled tile-major index: tiles of 128 rows x 64 k, 8192 ushort each.
__device__ __forceinline__ size_t swz_idx(int rb, int r, int kp, int nkt) {
    int kt = kp >> 6, kc = kp & 63;
    return ((size_t)(rb * nkt + kt)) * 8192 + r * 64 + (kc ^ ((r & 7) << 3));
}

__device__ __forceinline__ void gld16(const ushort_t* g, ushort_t* l) {
    __builtin_amdgcn_global_load_lds(
        (const __attribute__((address_space(1))) void*)g,
        (__attribute__((address_space(3))) void*)l, 16, 0, 0);
}

// ================= merged prep: prepx(vec) + prepWft + prepW1 + zero =================
__global__ void k_prep(const float* __restrict__ x, const float* __restrict__ ftW,
                       const float* __restrict__ W1f,
                       ushort_t* __restrict__ Ax, ushort_t* __restrict__ Bx,
                       ushort_t* __restrict__ B1,
                       int* __restrict__ cnt, int* __restrict__ cursor) {
    int bid = blockIdx.x, t = threadIdx.x;
    if (bid < 632) {                        // prepx: Ax[MPAD][256] = [xhi | xlo], 16B stores
        int gid = bid * 256 + t;            // n * 16 + chunk
        int n = gid >> 4, k0 = (gid & 15) * 8;
        float v[8];
        if (n < N_NODES) {
            #pragma unroll
            for (int u = 0; u < 8; u++) v[u] = x[n * DIN + k0 + u];
        } else {
            #pragma unroll
            for (int u = 0; u < 8; u++) v[u] = 0.f;
        }
        us8 hi, lo;
        #pragma unroll
        for (int u = 0; u < 8; u++) {
            ushort_t h = f2bf(v[u]);
            hi[u] = h;
            lo[u] = f2bf(v[u] - bf2f(h));
        }
        int rb = n >> 7, r = n & 127;
        *(us8*)(Ax + swz_idx(rb, r, k0, 4)) = hi;
        *(us8*)(Ax + swz_idx(rb, r, 128 + k0, 4)) = lo;
    } else if (bid < 888) {                 // prepWft: Bx[512][256] = [Whi | Whi]
        int i = (bid - 632) * 256 + t;
        int n = i >> 7, k = i & 127;
        ushort_t h = f2bf(ftW[k * DW + n]);
        int cb = n >> 7, rc = n & 127;
        Bx[swz_idx(cb, rc, k, 4)] = h;
        Bx[swz_idx(cb, rc, 128 + k, 4)] = h;
    } else if (bid < 1912) {                // prepW1: B1[512][1024] = [W1hi | W1hi]
        int i = (bid - 888) * 256 + t;
        int n = i >> 9, k = i & 511;
        ushort_t h = f2bf(W1f[k * DW + n]);
        int cb = n >> 7, rc = n & 127;
        B1[swz_idx(cb, rc, k, 16)] = h;
        B1[swz_idx(cb, rc, 512 + k, 16)] = h;
    } else {                                // zero cnt/cursor
        int i = (bid - 1912) * 256 + t;
        if (i < N_NODES) { cnt[i] = 0; cursor[i] = 0; }
    }
}

// ================= LDS-DMA double-buffered bf16 MFMA GEMM, 8 waves (+side work) =================
// C = A[MPAD][KT*64] @ B[512][KT*64]^T ; pre-swizzled tile-major operands.
// 128x128 tile, 512 threads: wave = 32 rows x 64 cols (acc[2][4]).
// EXTRA: 1 = CSR count, 2 = CSR scatter (blocks >= GEMM_BLKS, e = (bid-316)*512+t).
template<int KT, bool ATT, int EXTRA>
__global__ __launch_bounds__(512, 4) void k_tgemm(const ushort_t* __restrict__ A,
                                                  const ushort_t* __restrict__ Bm,
                                                  float* __restrict__ C,
                                                  ushort_t* __restrict__ Cb,
                                                  const float* __restrict__ asrc,
                                                  const float* __restrict__ adst,
                                                  float* __restrict__ aS,
                                                  float* __restrict__ aD,
                                                  const int* __restrict__ ei,
                                                  int* __restrict__ cnt,
                                                  const int* __restrict__ off,
                                                  int* __restrict__ cursor,
                                                  int* __restrict__ csrc) {
    __shared__ __align__(16) ushort_t As[2][8192];
    __shared__ __align__(16) ushort_t Bs[2][8192];
    int bid = blockIdx.x;
    if (bid >= GEMM_BLKS) {                 // ---- CSR side work ----
        int e = (bid - GEMM_BLKS) * 512 + threadIdx.x;
        if (e < N_EDGES) {
            if (EXTRA == 1) {
                atomicAdd(&cnt[ei[N_EDGES + e]], 1);
            } else {
                int d = ei[N_EDGES + e];
                int p = off[d] + atomicAdd(&cursor[d], 1);
                csrc[p] = ei[e];
            }
        }
        return;
    }
    int bx = bid >> 2, by = bid & 3;
    int t = threadIdx.x, w = t >> 6, l = t & 63;
    int lm = l & 15, g = l >> 4;
    int wr = w >> 1, wc = w & 1;            // 4 row-stripes x 2 col-stripes
    int rowbase = bx * 128;
    int colbase = by * 128;

    // staging: thread t covers 16B at offset t*8 us, rounds j add 4096 us
    const ushort_t* Abase = A + (size_t)bx * KT * 8192 + t * 8;
    const ushort_t* Bbase = Bm + (size_t)by * KT * 8192 + t * 8;

    f32x4 acc[2][4];
    #pragma unroll
    for (int r = 0; r < 2; r++)
        #pragma unroll
        for (int c = 0; c < 4; c++) acc[r][c] = (f32x4){0.f, 0.f, 0.f, 0.f};

    {   // prologue: tile 0 -> buf 0 (4 DMA/thread)
        #pragma unroll
        for (int j = 0; j < 2; ++j) {
            gld16(Abase + j * 4096, &As[0][j * 4096 + t * 8]);
            gld16(Bbase + j * 4096, &Bs[0][j * 4096 + t * 8]);
        }
    }

    int p = 0;
    for (int kt = 0; kt < KT; ++kt) {
        __builtin_amdgcn_s_barrier();       // all waves done reading buf[p^1]
        if (kt + 1 < KT) {
            const ushort_t* ga = Abase + (size_t)(kt + 1) * 8192;
            const ushort_t* gb = Bbase + (size_t)(kt + 1) * 8192;
            #pragma unroll
            for (int j = 0; j < 2; ++j) {
                gld16(ga + j * 4096, &As[p ^ 1][j * 4096 + t * 8]);
                gld16(gb + j * 4096, &Bs[p ^ 1][j * 4096 + t * 8]);
            }
            asm volatile("s_waitcnt vmcnt(4)" ::: "memory");   // tile kt landed
        } else {
            asm volatile("s_waitcnt vmcnt(0)" ::: "memory");
        }
        __builtin_amdgcn_s_barrier();       // ALL waves' tile-kt DMA complete
        const char* Ap = (const char*)As[p];
        const char* Bp = (const char*)Bs[p];
        #pragma unroll
        for (int ks = 0; ks < 2; ++ks) {
            bf16x8 af[2], bfr[4];
            #pragma unroll
            for (int r = 0; r < 2; ++r) {
                int row = wr * 32 + r * 16 + lm;
                af[r] = *(const bf16x8*)(Ap + row * 128 +
                                         ((ks * 64 + g * 16) ^ ((row & 7) << 4)));
            }
            #pragma unroll
            for (int c = 0; c < 4; ++c) {
                int col = wc * 64 + c * 16 + lm;
                bfr[c] = *(const bf16x8*)(Bp + col * 128 +
                                          ((ks * 64 + g * 16) ^ ((col & 7) << 4)));
            }
            #pragma unroll
            for (int r = 0; r < 2; ++r)
                #pragma unroll
                for (int c = 0; c < 4; ++c)
                    acc[r][c] = __builtin_amdgcn_mfma_f32_16x16x32_bf16(af[r], bfr[c], acc[r][c], 0, 0, 0);
        }
        p ^= 1;
    }

    // C/D map: col = lane&15, row = (lane>>4)*4 + q
    if (!ATT) {
        #pragma unroll
        for (int r = 0; r < 2; ++r) {
            int row0 = rowbase + wr * 32 + r * 16 + g * 4;
            #pragma unroll
            for (int c = 0; c < 4; ++c) {
                int col = colbase + wc * 64 + c * 16 + lm;
                #pragma unroll
                for (int q = 0; q < 4; ++q)
                    if (row0 + q < N_NODES) C[(size_t)(row0 + q) * DW + col] = acc[r][c][q];
            }
        }
    } else {
        int h = 2 * by + wc;                  // this wave's head
        float asv[4], adv[4];
        #pragma unroll
        for (int c = 0; c < 4; ++c) {
            asv[c] = asrc[h * NC + c * 16 + lm];
            adv[c] = adst[h * NC + c * 16 + lm];
        }
        #pragma unroll
        for (int r = 0; r < 2; ++r) {
            int row0 = rowbase + wr * 32 + r * 16 + g * 4;
            #pragma unroll
            for (int c = 0; c < 4; ++c) {
                int col = colbase + wc * 64 + c * 16 + lm;
                #pragma unroll
                for (int q = 0; q < 4; ++q)
                    if (row0 + q < N_NODES) Cb[(size_t)(row0 + q) * DW + col] = f2bf(acc[r][c][q]);
            }
            #pragma unroll
            for (int q = 0; q < 4; ++q) {
                float ss = acc[r][0][q] * asv[0] + acc[r][1][q] * asv[1] +
                           acc[r][2][q] * asv[2] + acc[r][3][q] * asv[3];
                float dd = acc[r][0][q] * adv[0] + acc[r][1][q] * adv[1] +
                           acc[r][2][q] * adv[2] + acc[r][3][q] * adv[3];
                #pragma unroll
                for (int m = 1; m < 16; m <<= 1) {
                    ss += __shfl_xor(ss, m, 64);
                    dd += __shfl_xor(dd, m, 64);
                }
                int row = row0 + q;
                if (lm == 0 && row < N_NODES) {
                    aS[row * NHEAD + h] = ss;
                    aD[row * NHEAD + h] = dd;
                }
            }
        }
    }
}

// ================= LN epilogue -> h0big[*][1024] = [hi | lo], vectorized (+ scan block) =================
__global__ __launch_bounds__(256) void k_ln_scan(const float* __restrict__ hpre,
                                                 const float* __restrict__ fb,
                                                 const float* __restrict__ g,
                                                 const float* __restrict__ beta,
                                                 ushort_t* __restrict__ h0big,
                                                 const int* __restrict__ cnt,
                                                 int* __restrict__ off) {
    __shared__ int ps[256];
    __shared__ float red[8];
    __shared__ __align__(16) ushort_t st[1024];
    int bid = blockIdx.x, t = threadIdx.x;
    if (bid == MPAD) {                       // ---- exclusive scan over cnt ----
        int base = t * 40;
        int loc[40];
        int s = 0;
        #pragma unroll
        for (int i = 0; i < 40; i++) {
            int idx = base + i;
            int v = idx < N_NODES ? cnt[idx] : 0;
            loc[i] = s; s += v;
        }
        ps[t] = s; __syncthreads();
        for (int o = 1; o < 256; o <<= 1) {
            int v = (t >= o) ? ps[t - o] : 0;
            __syncthreads();
            ps[t] += v;
            __syncthreads();
        }
        int pre = (t > 0) ? ps[t - 1] : 0;
        #pragma unroll
        for (int i = 0; i < 40; i++) {
            int idx = base + i;
            if (idx < N_NODES) off[idx] = pre + loc[i];
        }
        if (t == 255) off[N_NODES] = ps[255];
        return;
    }
    int n = bid;
    int rb = n >> 7, r = n & 127;
    if (n >= N_NODES) {
        if (t < 128) {
            int kp0 = t * 8;
            *(us8*)(h0big + ((size_t)(rb * 16 + (kp0 >> 6))) * 8192 + r * 64 +
                    ((kp0 & 63) ^ ((r & 7) << 3))) = (us8){0,0,0,0,0,0,0,0};
        }
        return;
    }
    float a0 = hpre[(size_t)n * DW + t] + fb[t];
    float a1 = hpre[(size_t)n * DW + t + 256] + fb[t + 256];
    float s = a0 + a1, sq = a0 * a0 + a1 * a1;
    for (int o = 32; o > 0; o >>= 1) { s += __shfl_down(s, o, 64); sq += __shfl_down(sq, o, 64); }
    int wid = t >> 6;
    if ((t & 63) == 0) { red[wid] = s; red[4 + wid] = sq; }
    __syncthreads();
    if (t == 0) {
        float ts = red[0] + red[1] + red[2] + red[3];
        float tq = red[4] + red[5] + red[6] + red[7];
        float mu = ts / DW;
        float var = tq / DW - mu * mu;
        red[0] = mu; red[1] = rsqrtf(var + 1e-5f);
    }
    __syncthreads();
    float mu = red[0], rs = red[1];
    float v0 = (a0 - mu) * rs * g[t] + beta[t];
    float v1 = (a1 - mu) * rs * g[t + 256] + beta[t + 256];
    v0 = v0 >= 0.f ? v0 : 0.2f * v0;
    v1 = v1 >= 0.f ? v1 : 0.2f * v1;
    ushort_t h0_ = f2bf(v0), l0_ = f2bf(v0 - bf2f(h0_));
    ushort_t h1_ = f2bf(v1), l1_ = f2bf(v1 - bf2f(h1_));
    st[t] = h0_;        st[256 + t] = h1_;      // hi occupies kp 0..511
    st[512 + t] = l0_;  st[768 + t] = l1_;      // lo occupies kp 512..1023
    __syncthreads();
    if (t < 128) {
        int kp0 = t * 8;
        *(us8*)(h0big + ((size_t)(rb * 16 + (kp0 >> 6))) * 8192 + r * 64 +
                ((kp0 & 63) ^ ((r & 7) << 3))) = *(const us8*)(st + kp0);
    }
}

// ================= layer-1 aggregation: bf16 gather, fused softmax+bias+BN+ReLU -> bf16 h2 =================
__global__ __launch_bounds__(256) void k_agg1csr(
    const int* __restrict__ csrc, const int* __restrict__ off,
    const ushort_t* __restrict__ h1b,
    const float* __restrict__ aS, const float* __restrict__ aD,
    const float* __restrict__ b1, const float* __restrict__ bnm,
    const float* __restrict__ bnv, const float* __restrict__ bng,
    const float* __restrict__ bnb, ushort_t* __restrict__ h2b)
{
    int n = blockIdx.x, t = threadIdx.x;
    int beg = off[n], end = off[n + 1];
    __shared__ float wls[64][NHEAD];
    __shared__ int   sls[64];
    __shared__ float aDn[NHEAD];
    __shared__ float dsum[NHEAD];
    if (t < NHEAD) { aDn[t] = aD[n * NHEAD + t]; dsum[t] = 0.f; }
    __syncthreads();
    float acc0 = 0.f, acc1 = 0.f, dpart = 0.f;
    int hA = t >> 5;                       // head of cols 2t, 2t+1
    for (int c = beg; c < end; c += 64) {
        int m = min(64, end - c);
        if (t < m) sls[t] = csrc[c + t];
        __syncthreads();
        for (int idx = t; idx < m * NHEAD; idx += 256) {
            int el = idx >> 3, h = idx & 7;
            float l = aS[sls[el] * NHEAD + h] + aDn[h];
            l = l >= 0.f ? l : 0.2f * l;
            float w = __expf(l);
            wls[el][h] = w;
            dpart += w;
        }
        __syncthreads();
        for (int el = 0; el < m; el++) {
            float w = wls[el][hA];
            unsigned v = *(const unsigned*)(h1b + (size_t)sls[el] * DW + 2 * t);
            acc0 += w * __builtin_bit_cast(float, v << 16);
            acc1 += w * __builtin_bit_cast(float, v & 0xffff0000u);
        }
        __syncthreads();
    }
    for (int o = 8; o < 64; o <<= 1) dpart += __shfl_down(dpart, o, 64);
    if ((t & 63) < NHEAD) atomicAdd(&dsum[t & 7], dpart);
    __syncthreads();
    float rd = dsum[hA] > 0.f ? 1.f / dsum[hA] : 0.f;
    int j0 = 2 * t, j1 = 2 * t + 1;
    float v0 = acc0 * rd + b1[j0];
    v0 = (v0 - bnm[j0]) * rsqrtf(bnv[j0] + 1e-5f) * bng[j0] + bnb[j0];
    v0 = v0 > 0.f ? v0 : 0.f;
    float v1 = acc1 * rd + b1[j1];
    v1 = (v1 - bnm[j1]) * rsqrtf(bnv[j1] + 1e-5f) * bng[j1] + bnb[j1];
    v1 = v1 > 0.f ? v1 : 0.f;
    unsigned pk = (unsigned)f2bf(v0) | ((unsigned)f2bf(v1) << 16);
    *(unsigned*)(h2b + (size_t)n * DW + 2 * t) = pk;
}

// ================= GEMM2 + fused att2 =================
__global__ __launch_bounds__(256) void k_gemm2att(const ushort_t* __restrict__ h2b,
                                                  const float* __restrict__ W2,
                                                  const float* __restrict__ as2,
                                                  const float* __restrict__ ad2,
                                                  float* __restrict__ gout,
                                                  float* __restrict__ aS,
                                                  float* __restrict__ aD) {
    __shared__ float Ws[DW * 16];
    __shared__ float gl[16][16];
    __shared__ float a2[32];
    int t = threadIdx.x;
    for (int i = t; i < DW * 16; i += 256) Ws[i] = W2[i];
    if (t < 16) a2[t] = as2[t];
    else if (t < 32) a2[t] = ad2[t - 16];
    __syncthreads();
    int nb = blockIdx.x * 16;
    int nl = t >> 4, j = t & 15;
    const bf16x8* hr = (const bf16x8*)(h2b + (size_t)(nb + nl) * DW);
    float acc = 0.f;
    for (int ks = 0; ks < DW / 8; ks++) {
        bf16x8 v = hr[ks];
        #pragma unroll
        for (int u = 0; u < 8; u++)
            acc += bf2f((ushort_t)v[u]) * Ws[(ks * 8 + u) * 16 + j];
    }
    gout[(nb + nl) * 16 + j] = acc;
    gl[nl][j] = acc;
    __syncthreads();
    if (j < 8) {
        aS[(nb + nl) * NHEAD + j] = gl[nl][2 * j] * a2[2 * j] + gl[nl][2 * j + 1] * a2[2 * j + 1];
    } else {
        int h = j - 8;
        aD[(nb + nl) * NHEAD + h] = gl[nl][2 * h] * a2[16 + 2 * h] + gl[nl][2 * h + 1] * a2[16 + 2 * h + 1];
    }
}

// ================= layer-2 aggregation, CSR, fused head-mean + b2 =================
__global__ __launch_bounds__(256) void k_agg2csr(
    const int* __restrict__ csrc, const int* __restrict__ off,
    const float* __restrict__ gbuf,
    const float* __restrict__ aS, const float* __restrict__ aD,
    const float* __restrict__ b2, float* __restrict__ outp)
{
    int t = threadIdx.x;
    int n = blockIdx.x * 4 + (t >> 6);
    int lane = t & 63;
    if (n >= N_NODES) return;
    int beg = off[n], end = off[n + 1];
    int j = lane & 15, slot = lane >> 4, h = j >> 1;
    float adn = aD[n * NHEAD + h];
    float acc = 0.f, den = 0.f;
    for (int c = beg + slot; c < end; c += 4) {
        int s = csrc[c];
        float l = aS[s * NHEAD + h] + adn;
        l = l >= 0.f ? l : 0.2f * l;
        float w = __expf(l);
        den += w;
        acc += w * gbuf[s * 16 + j];
    }
    acc += __shfl_down(acc, 16, 64); acc += __shfl_down(acc, 32, 64);
    den += __shfl_down(den, 16, 64); den += __shfl_down(den, 32, 64);
    float v = (lane < 16 && den > 0.f) ? acc / den : 0.f;
    v += __shfl_down(v, 2, 64);
    v += __shfl_down(v, 4, 64);
    v += __shfl_down(v, 8, 64);
    if (lane < 2) outp[n * 2 + lane] = v * 0.125f + b2[lane];
}

extern "C" void kernel_launch(void* const* d_in, const int* in_sizes, int n_in,
                              void* d_out, int out_size, void* d_ws, size_t ws_size,
                              hipStream_t stream) {
    const float* x    = (const float*)d_in[0];
    const int*   ei   = (const int*)d_in[1];
    const float* ftW  = (const float*)d_in[2];
    const float* ftb  = (const float*)d_in[3];
    const float* lng  = (const float*)d_in[4];
    const float* lnb  = (const float*)d_in[5];
    const float* W1   = (const float*)d_in[6];
    const float* as1  = (const float*)d_in[7];
    const float* ad1  = (const float*)d_in[8];
    const float* b1   = (const float*)d_in[9];
    const float* bng  = (const float*)d_in[10];
    const float* bnb  = (const float*)d_in[11];
    const float* bnm  = (const float*)d_in[12];
    const float* bnv  = (const float*)d_in[13];
    const float* W2   = (const float*)d_in[14];
    const float* as2  = (const float*)d_in[15];
    const float* ad2  = (const float*)d_in[16];
    const float* b2   = (const float*)d_in[17];
    float* out = (float*)d_out;

    // ---- workspace (float offsets), lifetime-aliased ----
    float* F = (float*)d_ws;
    ushort_t* Ax    = (ushort_t*)(F + 0);          // 79*4*8192 us = 1,294,336 f
    float*    gbuf  = F + 0;                       // 160,000 f (after Ax dead)
    ushort_t* Bx    = (ushort_t*)(F + 1294336);    // 65,536 f
    ushort_t* B1    = (ushort_t*)(F + 1359872);    // 262,144 f
    float*    hpre  = F + 1622016;                 // 10112*512 f
    ushort_t* h2b   = (ushort_t*)(F + 1622016);    // 10000*512 us (after ln)
    ushort_t* h0big = (ushort_t*)(F + 6799360);    // 79*16*8192 us = 5,177,344 f
    ushort_t* h1b   = (ushort_t*)(F + 11976704);   // 10000*512 us
    float*    aS1   = F + 14536704;                // 80,000 (reused layer 2)
    float*    aD1   = F + 14616704;                // 80,000
    int* cnt        = (int*)(F + 14696704);
    int* cursor     = (int*)(F + 14706704);
    int* off        = (int*)(F + 14716704);
    int* csrc       = (int*)(F + 14726705);        // -> end 14,886,705 f (~59.5 MB)

    // 1. merged prep (Ax-vec + Bx + B1 + zero)
    k_prep<<<1952, 256, 0, stream>>>(x, ftW, W1, Ax, Bx, B1, cnt, cursor);
    // 2. ft GEMM (K'=256) + CSR count    [313 extra 512-thread blocks]
    k_tgemm<4, false, 1><<<GEMM_BLKS + 313, 512, 0, stream>>>(
        Ax, Bx, hpre, nullptr, nullptr, nullptr, nullptr, nullptr,
        ei, cnt, nullptr, nullptr, nullptr);
    // 3. LN -> h0big (K'=1024 [hi|lo], vectorized) + CSR scan
    k_ln_scan<<<MPAD + 1, 256, 0, stream>>>(hpre, ftb, lng, lnb, h0big, cnt, off);
    // 4. GEMM1 (K'=1024) + fused att-dots + CSR scatter
    k_tgemm<16, true, 2><<<GEMM_BLKS + 313, 512, 0, stream>>>(
        h0big, B1, nullptr, h1b, as1, ad1, aS1, aD1,
        ei, nullptr, off, cursor, csrc);
    // 5. layer-1 aggregation (fused softmax + bias + BN + ReLU)
    k_agg1csr<<<N_NODES, 256, 0, stream>>>(csrc, off, h1b, aS1, aD1, b1, bnm, bnv, bng, bnb, h2b);
    // 6. GEMM2 + fused att2
    k_gemm2att<<<N_NODES / 16, 256, 0, stream>>>(h2b, W2, as2, ad2, gbuf, aS1, aD1);
    // 7. layer-2 aggregation (fused head-mean + b2)
    k_agg2csr<<<(N_NODES + 3) / 4, 256, 0, stream>>>(csrc, off, gbuf, aS1, aD1, b2, out);
}